// Round 1
// baseline (7442.958 us; speedup 1.0000x reference)
//
#include <hip/hip_runtime.h>
#include <math.h>

// Model constants (from reference): B=32, T=50000, P=100, D=512, H=16, L=6, C=256
// SCALES=[1,2,4], HS=5 heads/scale, KD=32, N=500 patches, FF=2048, EPS=1e-3.
//
// KEY INSIGHT: first layernorm is over a size-1 axis -> output == ln_in_b[0]
// everywhere (input tensor is dead). Therefore h is batch-independent and the
// whole network runs once on a (500 x 512) state; final row broadcast to B=32.

#define DD 512
#define NN 500
#define HSC 5
#define KDD 32
#define QKVN 160   // HS*KD
#define FF 2048
#define NL 6
#define NC 256
#define NB 32
#define LNEPS 1e-3f

__device__ __forceinline__ float gelu_exact(float x) {
    return 0.5f * x * (1.0f + erff(x * 0.70710678118654752f));
}

// ---------- setup ----------
__global__ void colsum_kernel(const float* __restrict__ pw, float* __restrict__ csum) {
    int d = blockIdx.x * blockDim.x + threadIdx.x;
    if (d < DD) {
        float s = 0.f;
        for (int p = 0; p < 100; ++p) s += pw[p * DD + d];
        csum[d] = s;
    }
}

__global__ void init_h(const float* __restrict__ csum, const float* __restrict__ pb,
                       const float* __restrict__ pos, const float* __restrict__ lnb,
                       float* __restrict__ h) {
    int idx = blockIdx.x * 256 + threadIdx.x;
    if (idx >= NN * DD) return;
    int d = idx & (DD - 1);
    h[idx] = lnb[0] * csum[d] + pb[d] + pos[idx];
}

// ---------- pooling (SAME avg_pool over s consecutive tokens) ----------
__global__ void pool_kernel(const float* __restrict__ h, float* __restrict__ out,
                            int s, int M) {
    int idx = blockIdx.x * 256 + threadIdx.x;  // over M*DD
    if (idx >= M * DD) return;
    int d = idx & (DD - 1), m = idx >> 9;
    float acc = 0.f;
    for (int t = 0; t < s; ++t) acc += h[(size_t)(m * s + t) * DD + d];
    out[idx] = acc / (float)s;
}

// ---------- generic tiled GEMM: C = A(MxK) @ B(KxN) + bias, optional GELU ----------
__global__ __launch_bounds__(256) void gemm_bias_act(
        const float* __restrict__ A, const float* __restrict__ B,
        const float* __restrict__ bias, float* __restrict__ C,
        int M, int N, int K, int act) {
    __shared__ float As[32][33];
    __shared__ float Bs[32][33];
    int tx = threadIdx.x, ty = threadIdx.y;
    int tid = ty * 16 + tx;
    int bm = blockIdx.y * 32, bn = blockIdx.x * 32;
    float acc00 = 0.f, acc01 = 0.f, acc10 = 0.f, acc11 = 0.f;
    for (int k0 = 0; k0 < K; k0 += 32) {
        for (int i = tid; i < 32 * 32; i += 256) {
            int m = i >> 5, kk = i & 31;
            float va = 0.f;
            if (bm + m < M) va = A[(size_t)(bm + m) * K + k0 + kk];
            As[kk][m] = va;
        }
        for (int i = tid; i < 32 * 32; i += 256) {
            int kk = i >> 5, n = i & 31;
            Bs[kk][n] = B[(size_t)(k0 + kk) * N + bn + n];
        }
        __syncthreads();
        #pragma unroll
        for (int kk = 0; kk < 32; ++kk) {
            float a0 = As[kk][ty * 2], a1 = As[kk][ty * 2 + 1];
            float b0 = Bs[kk][tx * 2], b1 = Bs[kk][tx * 2 + 1];
            acc00 += a0 * b0; acc01 += a0 * b1;
            acc10 += a1 * b0; acc11 += a1 * b1;
        }
        __syncthreads();
    }
    float accs[2][2] = {{acc00, acc01}, {acc10, acc11}};
    for (int im = 0; im < 2; ++im) {
        int m = bm + ty * 2 + im;
        if (m >= M) continue;
        for (int in = 0; in < 2; ++in) {
            int n = bn + tx * 2 + in;
            float v = accs[im][in] + bias[n];
            if (act == 1) v = gelu_exact(v);
            C[(size_t)m * N + n] = v;
        }
    }
}

// ---------- attention scores: sc[h,i,j] = (q[i,h,:] . k[j,h,:]) / sqrt(32) ----------
__global__ void scores_kernel(const float* __restrict__ q, const float* __restrict__ k,
                              float* __restrict__ sc, int n) {
    size_t idx = (size_t)blockIdx.x * 256 + threadIdx.x;
    size_t tot = (size_t)HSC * n * n;
    if (idx >= tot) return;
    int j = (int)(idx % n);
    size_t t = idx / n;
    int i = (int)(t % n);
    int h = (int)(t / n);
    const float* qp = q + (size_t)i * QKVN + h * KDD;
    const float* kp = k + (size_t)j * QKVN + h * KDD;
    float acc = 0.f;
    #pragma unroll
    for (int c = 0; c < KDD; ++c) acc += qp[c] * kp[c];
    sc[idx] = acc * 0.17677669529663687f;  // 1/sqrt(32)
}

// ---------- row softmax over last dim (block per row, 256 threads) ----------
__global__ void softmax_rows(float* __restrict__ sc, int n) {
    int row = blockIdx.x;
    float* p = sc + (size_t)row * n;
    int t = threadIdx.x;
    int lane = t & 63, wv = t >> 6;
    __shared__ float r[4];
    __shared__ float bmx, bsum;

    float mx = -1e30f;
    for (int j = t; j < n; j += 256) mx = fmaxf(mx, p[j]);
    for (int off = 32; off; off >>= 1) mx = fmaxf(mx, __shfl_down(mx, off));
    if (lane == 0) r[wv] = mx;
    __syncthreads();
    if (t == 0) bmx = fmaxf(fmaxf(r[0], r[1]), fmaxf(r[2], r[3]));
    __syncthreads();
    float m = bmx;
    float s = 0.f;
    for (int j = t; j < n; j += 256) {
        float e = expf(p[j] - m);
        p[j] = e;
        s += e;
    }
    for (int off = 32; off; off >>= 1) s += __shfl_down(s, off);
    if (lane == 0) r[wv] = s;
    __syncthreads();
    if (t == 0) bsum = 1.f / (r[0] + r[1] + r[2] + r[3]);
    __syncthreads();
    float inv = bsum;
    for (int j = t; j < n; j += 256) p[j] *= inv;
}

// ---------- o[i,h,c] = sum_j p[h,i,j] * v[j,h,c] ----------
__global__ void attn_o(const float* __restrict__ p, const float* __restrict__ v,
                       float* __restrict__ o, int n) {
    int idx = blockIdx.x * 256 + threadIdx.x;  // over n*160
    if (idx >= n * QKVN) return;
    int hk = idx % QKVN;
    int i = idx / QKVN;
    int h = hk / KDD;
    const float* pr = p + (size_t)h * n * n + (size_t)i * n;
    float acc = 0.f;
    for (int j = 0; j < n; ++j) acc += pr[j] * v[(size_t)j * QKVN + hk];
    o[idx] = acc;
}

// ---------- comb: out[n,:] = concat(a1x[n], a2x[n/2], a4x[n/4]) @ Wc + bc ----------
__global__ __launch_bounds__(256) void comb_gemm(
        const float* __restrict__ a0, const float* __restrict__ a1,
        const float* __restrict__ a2, const float* __restrict__ Wc,
        const float* __restrict__ bc, float* __restrict__ out) {
    __shared__ float As[32][33];
    __shared__ float Bs[32][33];
    int tx = threadIdx.x, ty = threadIdx.y;
    int tid = ty * 16 + tx;
    int bm = blockIdx.y * 32, bn = blockIdx.x * 32;
    float acc00 = 0.f, acc01 = 0.f, acc10 = 0.f, acc11 = 0.f;
    for (int k0 = 0; k0 < 3 * DD; k0 += 32) {
        int si = k0 >> 9;            // 512-aligned K-tiles: scale index constant per tile
        int dd0 = k0 & (DD - 1);
        const float* ap = (si == 0) ? a0 : ((si == 1) ? a1 : a2);
        int sh = si;                 // log2(scale): 0,1,2
        for (int i = tid; i < 32 * 32; i += 256) {
            int m = i >> 5, kk = i & 31;
            int row = bm + m;
            float va = 0.f;
            if (row < NN) va = ap[(size_t)(row >> sh) * DD + dd0 + kk];
            As[kk][m] = va;
        }
        for (int i = tid; i < 32 * 32; i += 256) {
            int kk = i >> 5, n = i & 31;
            Bs[kk][n] = Wc[(size_t)(k0 + kk) * DD + bn + n];
        }
        __syncthreads();
        #pragma unroll
        for (int kk = 0; kk < 32; ++kk) {
            float a0v = As[kk][ty * 2], a1v = As[kk][ty * 2 + 1];
            float b0 = Bs[kk][tx * 2], b1 = Bs[kk][tx * 2 + 1];
            acc00 += a0v * b0; acc01 += a0v * b1;
            acc10 += a1v * b0; acc11 += a1v * b1;
        }
        __syncthreads();
    }
    float accs[2][2] = {{acc00, acc01}, {acc10, acc11}};
    for (int im = 0; im < 2; ++im) {
        int m = bm + ty * 2 + im;
        if (m >= NN) continue;
        for (int in = 0; in < 2; ++in) {
            int n = bn + tx * 2 + in;
            out[(size_t)m * DD + n] = accs[im][in] + bc[n];
        }
    }
}

// ---------- h = LayerNorm(h + delta) * g + b  (block per row, 512 threads) ----------
__global__ void add_ln(float* __restrict__ h, const float* __restrict__ delta,
                       const float* __restrict__ gw, const float* __restrict__ bw) {
    int n = blockIdx.x;
    int t = threadIdx.x;  // 512
    float x = h[(size_t)n * DD + t] + delta[(size_t)n * DD + t];
    int lane = t & 63, wv = t >> 6;
    __shared__ float s1[8], s2[8];
    __shared__ float mb[2];
    float sum = x, sq = x * x;
    for (int off = 32; off; off >>= 1) {
        sum += __shfl_down(sum, off);
        sq  += __shfl_down(sq,  off);
    }
    if (lane == 0) { s1[wv] = sum; s2[wv] = sq; }
    __syncthreads();
    if (t == 0) {
        float a = 0.f, b = 0.f;
        for (int i = 0; i < 8; ++i) { a += s1[i]; b += s2[i]; }
        float mean = a / (float)DD;
        float var = b / (float)DD - mean * mean;
        mb[0] = mean;
        mb[1] = rsqrtf(var + LNEPS);
    }
    __syncthreads();
    h[(size_t)n * DD + t] = (x - mb[0]) * mb[1] * gw[t] + bw[t];
}

// ---------- head: g = mean_n h; softmax(g @ head_W + head_b); broadcast x32 ----------
__global__ void head_kernel(const float* __restrict__ h, const float* __restrict__ hw,
                            const float* __restrict__ hb, float* __restrict__ out) {
    __shared__ float gs[DD];
    __shared__ float r[4];
    __shared__ float bmx, bsum;
    int t = threadIdx.x;  // 256
    for (int d = t; d < DD; d += 256) {
        float s = 0.f;
        for (int n = 0; n < NN; ++n) s += h[(size_t)n * DD + d];
        gs[d] = s / (float)NN;
    }
    __syncthreads();
    float acc = hb[t];
    for (int d = 0; d < DD; ++d) acc += gs[d] * hw[(size_t)d * NC + t];
    int lane = t & 63, wv = t >> 6;
    float mx = acc;
    for (int off = 32; off; off >>= 1) mx = fmaxf(mx, __shfl_down(mx, off));
    if (lane == 0) r[wv] = mx;
    __syncthreads();
    if (t == 0) bmx = fmaxf(fmaxf(r[0], r[1]), fmaxf(r[2], r[3]));
    __syncthreads();
    float e = expf(acc - bmx);
    float s = e;
    for (int off = 32; off; off >>= 1) s += __shfl_down(s, off);
    if (lane == 0) r[wv] = s;
    __syncthreads();
    if (t == 0) bsum = 1.f / (r[0] + r[1] + r[2] + r[3]);
    __syncthreads();
    float pv = e * bsum;
    for (int b = 0; b < NB; ++b) out[(size_t)b * NC + t] = pv;
}

extern "C" void kernel_launch(void* const* d_in, const int* in_sizes, int n_in,
                              void* d_out, int out_size, void* d_ws, size_t ws_size,
                              hipStream_t stream) {
    // setup_inputs() dict order:
    const float* ln_in_b = (const float*)d_in[2];
    const float* patch_W = (const float*)d_in[3];
    const float* patch_b = (const float*)d_in[4];
    const float* pos_emb = (const float*)d_in[5];
    const float* Wq = (const float*)d_in[6];
    const float* bq = (const float*)d_in[7];
    const float* Wk = (const float*)d_in[8];
    const float* bk = (const float*)d_in[9];
    const float* Wv = (const float*)d_in[10];
    const float* bv = (const float*)d_in[11];
    const float* Wo = (const float*)d_in[12];
    const float* bo = (const float*)d_in[13];
    const float* Wc = (const float*)d_in[14];
    const float* bc = (const float*)d_in[15];
    const float* ln1_g = (const float*)d_in[16];
    const float* ln1_b = (const float*)d_in[17];
    const float* W1 = (const float*)d_in[18];
    const float* b1 = (const float*)d_in[19];
    const float* W2 = (const float*)d_in[20];
    const float* b2 = (const float*)d_in[21];
    const float* ln2_g = (const float*)d_in[22];
    const float* ln2_b = (const float*)d_in[23];
    const float* head_W = (const float*)d_in[24];
    const float* head_b = (const float*)d_in[25];
    float* out = (float*)d_out;

    // workspace layout (floats) — ~15.3 MB total
    float* ws = (float*)d_ws;
    float* h      = ws;               // 256000
    float* csum   = h + 256000;       // 512
    float* pooled = csum + 512;       // 256000
    float* q      = pooled + 256000;  // 80000
    float* k      = q + 80000;        // 80000
    float* v      = k + 80000;        // 80000
    float* sc     = v + 80000;        // 1250000
    float* o      = sc + 1250000;     // 80000
    float* a0     = o + 80000;        // 256000
    float* a1     = a0 + 256000;      // 128000
    float* a2     = a1 + 128000;      // 64000
    float* tmp    = a2 + 64000;       // 256000
    float* f      = tmp + 256000;     // 1024000

    dim3 blk2d(16, 16);

    colsum_kernel<<<1, 512, 0, stream>>>(patch_W, csum);
    init_h<<<(NN * DD + 255) / 256, 256, 0, stream>>>(csum, patch_b, pos_emb, ln_in_b, h);

    static const int scales_[3] = {1, 2, 4};
    float* aouts[3] = {a0, a1, a2};

    for (int l = 0; l < NL; ++l) {
        for (int si = 0; si < 3; ++si) {
            int s = scales_[si];
            int n = NN / s;
            const float* x = h;
            if (s > 1) {
                pool_kernel<<<(n * DD + 255) / 256, 256, 0, stream>>>(h, pooled, s, n);
                x = pooled;
            }
            size_t w = (size_t)(l * 3 + si);
            dim3 gq(QKVN / 32, (n + 31) / 32);
            gemm_bias_act<<<gq, blk2d, 0, stream>>>(x, Wq + w * DD * QKVN, bq + w * QKVN, q, n, QKVN, DD, 0);
            gemm_bias_act<<<gq, blk2d, 0, stream>>>(x, Wk + w * DD * QKVN, bk + w * QKVN, k, n, QKVN, DD, 0);
            gemm_bias_act<<<gq, blk2d, 0, stream>>>(x, Wv + w * DD * QKVN, bv + w * QKVN, v, n, QKVN, DD, 0);
            size_t tsc = (size_t)HSC * n * n;
            scores_kernel<<<(unsigned)((tsc + 255) / 256), 256, 0, stream>>>(q, k, sc, n);
            softmax_rows<<<HSC * n, 256, 0, stream>>>(sc, n);
            attn_o<<<(n * QKVN + 255) / 256, 256, 0, stream>>>(sc, v, o, n);
            dim3 ga(DD / 32, (n + 31) / 32);
            gemm_bias_act<<<ga, blk2d, 0, stream>>>(o, Wo + w * QKVN * DD, bo + w * DD, aouts[si], n, DD, QKVN, 0);
        }
        comb_gemm<<<dim3(DD / 32, (NN + 31) / 32), blk2d, 0, stream>>>(
            a0, a1, a2, Wc + (size_t)l * 3 * DD * DD, bc + (size_t)l * DD, tmp);
        add_ln<<<NN, DD, 0, stream>>>(h, tmp, ln1_g + (size_t)l * DD, ln1_b + (size_t)l * DD);
        gemm_bias_act<<<dim3(FF / 32, (NN + 31) / 32), blk2d, 0, stream>>>(
            h, W1 + (size_t)l * DD * FF, b1 + (size_t)l * FF, f, NN, FF, DD, 1);
        gemm_bias_act<<<dim3(DD / 32, (NN + 31) / 32), blk2d, 0, stream>>>(
            f, W2 + (size_t)l * FF * DD, b2 + (size_t)l * DD, tmp, NN, DD, FF, 0);
        add_ln<<<NN, DD, 0, stream>>>(h, tmp, ln2_g + (size_t)l * DD, ln2_b + (size_t)l * DD);
    }
    head_kernel<<<1, 256, 0, stream>>>(h, head_W, head_b, out);
}

// Round 2
// 4685.021 us; speedup vs baseline: 1.5887x; 1.5887x over previous
//
#include <hip/hip_runtime.h>
#include <math.h>

// Model constants: B=32, T=50000, P=100, D=512, H=16, L=6, C=256
// SCALES=[1,2,4], HS=5 heads/scale, KD=32, N=500 patches, FF=2048, EPS=1e-3.
//
// KEY INSIGHT (round 0, verified absmax=0.0): first layernorm is over a
// size-1 axis -> output == ln_in_b[0] everywhere (input tensor is dead).
// h is batch-independent; network runs once on (500 x 512); row broadcast x32.
//
// Round 1: GEMM engine rebuilt. Old 32x32-tile GEMM ran 1 wave/SIMD
// (occupancy 11.8%, VALUBusy 7%) -> pure latency bind. New engine:
// 8 rows x 64 cols per block, K split across the 4 waves, LDS reduce.

#define DD 512
#define NN 500
#define HSC 5
#define KDD 32
#define QKVN 160   // HS*KD
#define FF 2048
#define NL 6
#define NC 256
#define NB 32
#define LNEPS 1e-3f
#define TM 8       // rows per block
#define KC 256     // K chunk staged in LDS

__device__ __forceinline__ float gelu_exact(float x) {
    return 0.5f * x * (1.0f + erff(x * 0.70710678118654752f));
}

// ---------- setup ----------
__global__ void colsum_kernel(const float* __restrict__ pw, float* __restrict__ csum) {
    int d = blockIdx.x * blockDim.x + threadIdx.x;
    if (d < DD) {
        float s = 0.f;
        for (int p = 0; p < 100; ++p) s += pw[p * DD + d];
        csum[d] = s;
    }
}

__global__ void init_h(const float* __restrict__ csum, const float* __restrict__ pb,
                       const float* __restrict__ pos, const float* __restrict__ lnb,
                       float* __restrict__ h) {
    int idx = blockIdx.x * 256 + threadIdx.x;
    if (idx >= NN * DD) return;
    int d = idx & (DD - 1);
    h[idx] = lnb[0] * csum[d] + pb[d] + pos[idx];
}

// ---------- pooling ----------
__global__ void pool_kernel(const float* __restrict__ h, float* __restrict__ out,
                            int s, int M) {
    int idx = blockIdx.x * 256 + threadIdx.x;
    if (idx >= M * DD) return;
    int d = idx & (DD - 1), m = idx >> 9;
    float acc = 0.f;
    for (int t = 0; t < s; ++t) acc += h[(size_t)(m * s + t) * DD + d];
    out[idx] = acc / (float)s;
}

// ---------- GEMM engine: block = 8 rows x 64 cols, K 4-way wave-split ----------
// A: MxK row-major. B: KxN row-major. C = A@B + bias (+gelu if act).
__device__ __forceinline__ void gemm2_body(
        const float* __restrict__ A, const float* __restrict__ B,
        const float* __restrict__ bias, float* __restrict__ C,
        int M, int N, int K, int act) {
    __shared__ float As[KC][TM];        // 8 KB  (As[kk][r] -> b128-pair broadcast)
    __shared__ float red[4][TM][64];    // 8 KB
    int tid = threadIdx.x;
    int w = tid >> 6, lane = tid & 63;
    int bn = blockIdx.x * 64;
    int bm = blockIdx.y * TM;
    int col = bn + lane;
    bool colok = (col < N);
    float acc[TM];
    #pragma unroll
    for (int r = 0; r < TM; ++r) acc[r] = 0.f;

    for (int k0 = 0; k0 < K; k0 += KC) {
        // stage A[bm..bm+7][k0..k0+KC) with zero-fill
        #pragma unroll
        for (int i = tid; i < TM * KC; i += 256) {
            int r = i >> 8;           // i / KC
            int kk = i & (KC - 1);
            int row = bm + r;
            int k = k0 + kk;
            As[kk][r] = (row < M && k < K) ? A[(size_t)row * K + k] : 0.f;
        }
        __syncthreads();
        int kbeg = w * (KC / 4);      // 64 k-steps per wave
        if (colok) {
            if (k0 + KC <= K) {
                #pragma unroll 8
                for (int kk = kbeg; kk < kbeg + KC / 4; ++kk) {
                    float bv = B[(size_t)(k0 + kk) * N + col];
                    #pragma unroll
                    for (int r = 0; r < TM; ++r) acc[r] += As[kk][r] * bv;
                }
            } else {
                for (int kk = kbeg; kk < kbeg + KC / 4; ++kk) {
                    int k = k0 + kk;
                    float bv = (k < K) ? B[(size_t)k * N + col] : 0.f;
                    #pragma unroll
                    for (int r = 0; r < TM; ++r) acc[r] += As[kk][r] * bv;
                }
            }
        }
        __syncthreads();
    }
    #pragma unroll
    for (int r = 0; r < TM; ++r) red[w][r][lane] = acc[r];
    __syncthreads();
    #pragma unroll
    for (int o = tid; o < TM * 64; o += 256) {
        int r = o >> 6, c = o & 63;
        int row = bm + r, cc = bn + c;
        if (row < M && cc < N) {
            float v = red[0][r][c] + red[1][r][c] + red[2][r][c] + red[3][r][c] + bias[cc];
            if (act) v = gelu_exact(v);
            C[(size_t)row * N + cc] = v;
        }
    }
}

__global__ __launch_bounds__(256) void gemm2(
        const float* __restrict__ A, const float* __restrict__ B,
        const float* __restrict__ bias, float* __restrict__ C,
        int M, int N, int K, int act) {
    gemm2_body(A, B, bias, C, M, N, K, act);
}

// QKV fused: blockIdx.z selects q/k/v
__global__ __launch_bounds__(256) void gemm2_qkv(
        const float* __restrict__ X,
        const float* __restrict__ Wq, const float* __restrict__ bq, float* __restrict__ q,
        const float* __restrict__ Wk, const float* __restrict__ bk, float* __restrict__ k,
        const float* __restrict__ Wv, const float* __restrict__ bv, float* __restrict__ v,
        int n) {
    const float* W; const float* b; float* o;
    if (blockIdx.z == 0)      { W = Wq; b = bq; o = q; }
    else if (blockIdx.z == 1) { W = Wk; b = bk; o = k; }
    else                      { W = Wv; b = bv; o = v; }
    gemm2_body(X, W, b, o, n, QKVN, DD, 0);
}

// comb: A = concat(a0[n], a1[n/2], a2[n/4]) along K (1536), gathered on the fly
__global__ __launch_bounds__(256) void comb2(
        const float* __restrict__ a0, const float* __restrict__ a1,
        const float* __restrict__ a2, const float* __restrict__ Wc,
        const float* __restrict__ bc, float* __restrict__ out) {
    __shared__ float As[KC][TM];
    __shared__ float red[4][TM][64];
    int tid = threadIdx.x;
    int w = tid >> 6, lane = tid & 63;
    int bn = blockIdx.x * 64;
    int bm = blockIdx.y * TM;
    int col = bn + lane;
    float acc[TM];
    #pragma unroll
    for (int r = 0; r < TM; ++r) acc[r] = 0.f;

    for (int k0 = 0; k0 < 3 * DD; k0 += KC) {   // 6 chunks, 512-aligned scale regions
        int si = k0 >> 9;                        // 0,0,1,1,2,2
        int dd0 = k0 & (DD - 1);                 // 0,256,0,256,0,256
        const float* ap = (si == 0) ? a0 : ((si == 1) ? a1 : a2);
        #pragma unroll
        for (int i = tid; i < TM * KC; i += 256) {
            int r = i >> 8;
            int kk = i & (KC - 1);
            int row = bm + r;
            As[kk][r] = (row < NN) ? ap[(size_t)(row >> si) * DD + dd0 + kk] : 0.f;
        }
        __syncthreads();
        int kbeg = w * (KC / 4);
        #pragma unroll 8
        for (int kk = kbeg; kk < kbeg + KC / 4; ++kk) {
            float bv = Wc[(size_t)(k0 + kk) * DD + col];
            #pragma unroll
            for (int r = 0; r < TM; ++r) acc[r] += As[kk][r] * bv;
        }
        __syncthreads();
    }
    #pragma unroll
    for (int r = 0; r < TM; ++r) red[w][r][lane] = acc[r];
    __syncthreads();
    #pragma unroll
    for (int o = tid; o < TM * 64; o += 256) {
        int r = o >> 6, c = o & 63;
        int row = bm + r;
        if (row < NN)
            out[(size_t)row * DD + bn + c] =
                red[0][r][c] + red[1][r][c] + red[2][r][c] + red[3][r][c] + bc[bn + c];
    }
}

// ---------- attention scores ----------
__global__ void scores_kernel(const float* __restrict__ q, const float* __restrict__ k,
                              float* __restrict__ sc, int n) {
    size_t idx = (size_t)blockIdx.x * 256 + threadIdx.x;
    size_t tot = (size_t)HSC * n * n;
    if (idx >= tot) return;
    int j = (int)(idx % n);
    size_t t = idx / n;
    int i = (int)(t % n);
    int h = (int)(t / n);
    const float* qp = q + (size_t)i * QKVN + h * KDD;
    const float* kp = k + (size_t)j * QKVN + h * KDD;
    float acc = 0.f;
    #pragma unroll
    for (int c = 0; c < KDD; ++c) acc += qp[c] * kp[c];
    sc[idx] = acc * 0.17677669529663687f;  // 1/sqrt(32)
}

// ---------- row softmax ----------
__global__ void softmax_rows(float* __restrict__ sc, int n) {
    int row = blockIdx.x;
    float* p = sc + (size_t)row * n;
    int t = threadIdx.x;
    int lane = t & 63, wv = t >> 6;
    __shared__ float r[4];
    __shared__ float bmx, bsum;
    float mx = -1e30f;
    for (int j = t; j < n; j += 256) mx = fmaxf(mx, p[j]);
    for (int off = 32; off; off >>= 1) mx = fmaxf(mx, __shfl_down(mx, off));
    if (lane == 0) r[wv] = mx;
    __syncthreads();
    if (t == 0) bmx = fmaxf(fmaxf(r[0], r[1]), fmaxf(r[2], r[3]));
    __syncthreads();
    float m = bmx;
    float s = 0.f;
    for (int j = t; j < n; j += 256) {
        float e = expf(p[j] - m);
        p[j] = e;
        s += e;
    }
    for (int off = 32; off; off >>= 1) s += __shfl_down(s, off);
    if (lane == 0) r[wv] = s;
    __syncthreads();
    if (t == 0) bsum = 1.f / (r[0] + r[1] + r[2] + r[3]);
    __syncthreads();
    float inv = bsum;
    for (int j = t; j < n; j += 256) p[j] *= inv;
}

// ---------- o[i,h,c] = sum_j p[h,i,j] * v[j,h,c] ----------
__global__ void attn_o(const float* __restrict__ p, const float* __restrict__ v,
                       float* __restrict__ o, int n) {
    int idx = blockIdx.x * 256 + threadIdx.x;
    if (idx >= n * QKVN) return;
    int hk = idx % QKVN;
    int i = idx / QKVN;
    int h = hk / KDD;
    const float* pr = p + (size_t)h * n * n + (size_t)i * n;
    float acc = 0.f;
    for (int j = 0; j < n; ++j) acc += pr[j] * v[(size_t)j * QKVN + hk];
    o[idx] = acc;
}

// ---------- h = LayerNorm(h + delta) * g + b ----------
__global__ void add_ln(float* __restrict__ h, const float* __restrict__ delta,
                       const float* __restrict__ gw, const float* __restrict__ bw) {
    int n = blockIdx.x;
    int t = threadIdx.x;  // 512
    float x = h[(size_t)n * DD + t] + delta[(size_t)n * DD + t];
    int lane = t & 63, wv = t >> 6;
    __shared__ float s1[8], s2[8];
    __shared__ float mb[2];
    float sum = x, sq = x * x;
    for (int off = 32; off; off >>= 1) {
        sum += __shfl_down(sum, off);
        sq  += __shfl_down(sq,  off);
    }
    if (lane == 0) { s1[wv] = sum; s2[wv] = sq; }
    __syncthreads();
    if (t == 0) {
        float a = 0.f, b = 0.f;
        for (int i = 0; i < 8; ++i) { a += s1[i]; b += s2[i]; }
        float mean = a / (float)DD;
        float var = b / (float)DD - mean * mean;
        mb[0] = mean;
        mb[1] = rsqrtf(var + LNEPS);
    }
    __syncthreads();
    h[(size_t)n * DD + t] = (x - mb[0]) * mb[1] * gw[t] + bw[t];
}

// ---------- head ----------
__global__ void head_kernel(const float* __restrict__ h, const float* __restrict__ hw,
                            const float* __restrict__ hb, float* __restrict__ out) {
    __shared__ float gs[DD];
    __shared__ float r[4];
    __shared__ float bmx, bsum;
    int t = threadIdx.x;  // 256
    for (int d = t; d < DD; d += 256) {
        float s = 0.f;
        for (int n = 0; n < NN; ++n) s += h[(size_t)n * DD + d];
        gs[d] = s / (float)NN;
    }
    __syncthreads();
    float acc = hb[t];
    for (int d = 0; d < DD; ++d) acc += gs[d] * hw[(size_t)d * NC + t];
    int lane = t & 63, wv = t >> 6;
    float mx = acc;
    for (int off = 32; off; off >>= 1) mx = fmaxf(mx, __shfl_down(mx, off));
    if (lane == 0) r[wv] = mx;
    __syncthreads();
    if (t == 0) bmx = fmaxf(fmaxf(r[0], r[1]), fmaxf(r[2], r[3]));
    __syncthreads();
    float e = expf(acc - bmx);
    float s = e;
    for (int off = 32; off; off >>= 1) s += __shfl_down(s, off);
    if (lane == 0) r[wv] = s;
    __syncthreads();
    if (t == 0) bsum = 1.f / (r[0] + r[1] + r[2] + r[3]);
    __syncthreads();
    float pv = e * bsum;
    for (int b = 0; b < NB; ++b) out[(size_t)b * NC + t] = pv;
}

extern "C" void kernel_launch(void* const* d_in, const int* in_sizes, int n_in,
                              void* d_out, int out_size, void* d_ws, size_t ws_size,
                              hipStream_t stream) {
    const float* ln_in_b = (const float*)d_in[2];
    const float* patch_W = (const float*)d_in[3];
    const float* patch_b = (const float*)d_in[4];
    const float* pos_emb = (const float*)d_in[5];
    const float* Wq = (const float*)d_in[6];
    const float* bq = (const float*)d_in[7];
    const float* Wk = (const float*)d_in[8];
    const float* bk = (const float*)d_in[9];
    const float* Wv = (const float*)d_in[10];
    const float* bv = (const float*)d_in[11];
    const float* Wo = (const float*)d_in[12];
    const float* bo = (const float*)d_in[13];
    const float* Wc = (const float*)d_in[14];
    const float* bc = (const float*)d_in[15];
    const float* ln1_g = (const float*)d_in[16];
    const float* ln1_b = (const float*)d_in[17];
    const float* W1 = (const float*)d_in[18];
    const float* b1 = (const float*)d_in[19];
    const float* W2 = (const float*)d_in[20];
    const float* b2 = (const float*)d_in[21];
    const float* ln2_g = (const float*)d_in[22];
    const float* ln2_b = (const float*)d_in[23];
    const float* head_W = (const float*)d_in[24];
    const float* head_b = (const float*)d_in[25];
    float* out = (float*)d_out;

    float* ws = (float*)d_ws;
    float* h      = ws;               // 256000
    float* csum   = h + 256000;       // 512
    float* pooled = csum + 512;       // 256000
    float* q      = pooled + 256000;  // 80000
    float* k      = q + 80000;        // 80000
    float* v      = k + 80000;        // 80000
    float* sc     = v + 80000;        // 1250000
    float* o      = sc + 1250000;     // 80000
    float* a0     = o + 80000;        // 256000
    float* a1     = a0 + 256000;      // 128000
    float* a2     = a1 + 128000;      // 64000
    float* tmp    = a2 + 64000;       // 256000
    float* f      = tmp + 256000;     // 1024000

    colsum_kernel<<<1, 512, 0, stream>>>(patch_W, csum);
    init_h<<<(NN * DD + 255) / 256, 256, 0, stream>>>(csum, patch_b, pos_emb, ln_in_b, h);

    static const int scales_[3] = {1, 2, 4};
    float* aouts[3] = {a0, a1, a2};

    for (int l = 0; l < NL; ++l) {
        for (int si = 0; si < 3; ++si) {
            int s = scales_[si];
            int n = NN / s;
            const float* x = h;
            if (s > 1) {
                pool_kernel<<<(n * DD + 255) / 256, 256, 0, stream>>>(h, pooled, s, n);
                x = pooled;
            }
            size_t w = (size_t)(l * 3 + si);
            dim3 gq((QKVN + 63) / 64, (n + TM - 1) / TM, 3);
            gemm2_qkv<<<gq, 256, 0, stream>>>(
                x,
                Wq + w * DD * QKVN, bq + w * QKVN, q,
                Wk + w * DD * QKVN, bk + w * QKVN, k,
                Wv + w * DD * QKVN, bv + w * QKVN, v, n);
            size_t tsc = (size_t)HSC * n * n;
            scores_kernel<<<(unsigned)((tsc + 255) / 256), 256, 0, stream>>>(q, k, sc, n);
            softmax_rows<<<HSC * n, 256, 0, stream>>>(sc, n);
            attn_o<<<(n * QKVN + 255) / 256, 256, 0, stream>>>(sc, v, o, n);
            gemm2<<<dim3(DD / 64, (n + TM - 1) / TM), 256, 0, stream>>>(
                o, Wo + w * QKVN * DD, bo + w * DD, aouts[si], n, DD, QKVN, 0);
        }
        comb2<<<dim3(DD / 64, (NN + TM - 1) / TM), 256, 0, stream>>>(
            a0, a1, a2, Wc + (size_t)l * 3 * DD * DD, bc + (size_t)l * DD, tmp);
        add_ln<<<NN, DD, 0, stream>>>(h, tmp, ln1_g + (size_t)l * DD, ln1_b + (size_t)l * DD);
        gemm2<<<dim3(FF / 64, (NN + TM - 1) / TM), 256, 0, stream>>>(
            h, W1 + (size_t)l * DD * FF, b1 + (size_t)l * FF, f, NN, FF, DD, 1);
        gemm2<<<dim3(DD / 64, (NN + TM - 1) / TM), 256, 0, stream>>>(
            f, W2 + (size_t)l * FF * DD, b2 + (size_t)l * DD, tmp, NN, DD, FF, 0);
        add_ln<<<NN, DD, 0, stream>>>(h, tmp, ln2_g + (size_t)l * DD, ln2_b + (size_t)l * DD);
    }
    head_kernel<<<1, 256, 0, stream>>>(h, head_W, head_b, out);
}

// Round 3
// 2087.332 us; speedup vs baseline: 3.5658x; 2.2445x over previous
//
#include <hip/hip_runtime.h>
#include <math.h>

// Model constants: B=32, T=50000, P=100, D=512, H=16, L=6, C=256
// SCALES=[1,2,4], HS=5 heads/scale, KD=32, N=500 patches, FF=2048, EPS=1e-3.
//
// KEY INSIGHT (round 0, verified absmax=0.0): first layernorm is over a
// size-1 axis -> output == ln_in_b[0] everywhere (input tensor is dead).
// h is batch-independent; network runs once on (500 x 512); row broadcast x32.
//
// Round 2 post-mortem: column-per-lane GEMM had ~1 load in flight per CU
// (VALUBusy 4.4%, 85 GB/s, 516k cycles vs 16k cycles of FMA work). Round 3:
// LDS-tiled GEMM (128x64 tile, 8x4 microtile, float4 loads, reg-prefetch)
// with K-split across blockIdx.z for parallelism + reduce epilogues.

#define DD 512
#define NN 500
#define HSC 5
#define KDD 32
#define QKVN 160   // HS*KD
#define QKV3 480
#define FF 2048
#define NL 6
#define NC 256
#define NB 32
#define LNEPS 1e-3f

#define BM 128
#define BN 64
#define KCH 32

__device__ __forceinline__ float gelu_exact(float x) {
    return 0.5f * x * (1.0f + erff(x * 0.70710678118654752f));
}

// ---------- setup ----------
__global__ void colsum_kernel(const float* __restrict__ pw, float* __restrict__ csum) {
    int d = blockIdx.x * blockDim.x + threadIdx.x;
    if (d < DD) {
        float s = 0.f;
        for (int p = 0; p < 100; ++p) s += pw[p * DD + d];
        csum[d] = s;
    }
}

__global__ void init_h(const float* __restrict__ csum, const float* __restrict__ pb,
                       const float* __restrict__ pos, const float* __restrict__ lnb,
                       float* __restrict__ h) {
    int idx = blockIdx.x * 256 + threadIdx.x;
    if (idx >= NN * DD) return;
    int d = idx & (DD - 1);
    h[idx] = lnb[0] * csum[d] + pb[d] + pos[idx];
}

// ---------- tiled GEMM engine ----------
// C_part = A(MxK slice ks..kend)@B + 0 ; A optionally row-pooled (avg of
// pool_s consecutive rows of the source). Tiles: BM=128 x BN=64, KC=32.
// 256 threads, 8 rows x 4 cols per thread. Partial written to part[M*N].

__device__ __forceinline__ void stage_load(
        const float* __restrict__ A, int lda, int pool_s, float inv_pool,
        const float* __restrict__ B, int ldb,
        int M, int N, int bm, int bn, int k0,
        int am, int akv, int bk, int bn4,
        float4* aR, float4* bR) {
    #pragma unroll
    for (int p = 0; p < 4; ++p) {
        int row = bm + p * 32 + am;
        float4 v = make_float4(0.f, 0.f, 0.f, 0.f);
        if (row < M) {
            const float* ap = A + (size_t)row * pool_s * lda + k0 + akv * 4;
            v = *(const float4*)ap;
            for (int t = 1; t < pool_s; ++t) {
                const float4 u = *(const float4*)(ap + (size_t)t * lda);
                v.x += u.x; v.y += u.y; v.z += u.z; v.w += u.w;
            }
            v.x *= inv_pool; v.y *= inv_pool; v.z *= inv_pool; v.w *= inv_pool;
        }
        aR[p] = v;
    }
    int col = bn + bn4 * 4;
    #pragma unroll
    for (int p = 0; p < 2; ++p) {
        int kk = p * 16 + bk;
        float4 v = make_float4(0.f, 0.f, 0.f, 0.f);
        if (col < N) v = *(const float4*)(B + (size_t)(k0 + kk) * ldb + col);
        bR[p] = v;
    }
}

__device__ __forceinline__ void gemm_part_body(
        const float* __restrict__ A, int lda, int pool_s,
        const float* __restrict__ B, int ldb,
        float* __restrict__ part, int M, int N, int ks, int kend) {
    __shared__ float As[KCH][132];   // padded: conflict-free b128 reads
    __shared__ float Bs[KCH][68];
    int tid = threadIdx.x;
    int tx = tid & 15, ty = tid >> 4;
    int bn = blockIdx.x * BN, bm = blockIdx.y * BM;
    int am = tid >> 3, akv = tid & 7;     // A stage: 8 float4 per row-chunk
    int bk = tid >> 4, bn4 = tid & 15;    // B stage
    float inv_pool = 1.0f / (float)pool_s;

    float acc[8][4];
    #pragma unroll
    for (int u = 0; u < 8; ++u)
        #pragma unroll
        for (int v = 0; v < 4; ++v) acc[u][v] = 0.f;

    float4 aR[4], bR[2];
    stage_load(A, lda, pool_s, inv_pool, B, ldb, M, N, bm, bn, ks,
               am, akv, bk, bn4, aR, bR);
    int nch = (kend - ks) / KCH;

    for (int c = 0; c < nch; ++c) {
        __syncthreads();
        #pragma unroll
        for (int p = 0; p < 4; ++p) {
            int m = p * 32 + am;
            As[akv * 4 + 0][m] = aR[p].x;
            As[akv * 4 + 1][m] = aR[p].y;
            As[akv * 4 + 2][m] = aR[p].z;
            As[akv * 4 + 3][m] = aR[p].w;
        }
        #pragma unroll
        for (int p = 0; p < 2; ++p)
            *(float4*)&Bs[p * 16 + bk][bn4 * 4] = bR[p];
        __syncthreads();
        if (c + 1 < nch)
            stage_load(A, lda, pool_s, inv_pool, B, ldb, M, N, bm, bn,
                       ks + (c + 1) * KCH, am, akv, bk, bn4, aR, bR);
        #pragma unroll
        for (int kk = 0; kk < KCH; ++kk) {
            float4 b  = *(const float4*)&Bs[kk][tx * 4];
            float4 al = *(const float4*)&As[kk][ty * 8];
            float4 ah = *(const float4*)&As[kk][ty * 8 + 4];
            float a8[8] = {al.x, al.y, al.z, al.w, ah.x, ah.y, ah.z, ah.w};
            float b4[4] = {b.x, b.y, b.z, b.w};
            #pragma unroll
            for (int u = 0; u < 8; ++u)
                #pragma unroll
                for (int v = 0; v < 4; ++v)
                    acc[u][v] += a8[u] * b4[v];
        }
    }
    int col = bn + tx * 4;
    if (col < N) {
        #pragma unroll
        for (int u = 0; u < 8; ++u) {
            int row = bm + ty * 8 + u;
            if (row < M) {
                float4 o;
                o.x = acc[u][0]; o.y = acc[u][1]; o.z = acc[u][2]; o.w = acc[u][3];
                *(float4*)&part[(size_t)row * N + col] = o;
            }
        }
    }
}

// generic: grid (ceil(N/64), ceil(M/128), S); requires K % S == 0, (K/S) % 32 == 0
__global__ __launch_bounds__(256) void gemm_part(
        const float* __restrict__ A, int lda, int pool_s,
        const float* __restrict__ B, int ldb,
        float* __restrict__ part, int M, int N, int K, int S) {
    int s = blockIdx.z;
    int kq = K / S;
    gemm_part_body(A, lda, pool_s, B, ldb, part + (size_t)s * M * N,
                   M, N, s * kq, s * kq + kq);
}

// QKV: grid z = which*S + s ; writes part[(which*S+s)][n*160]
__global__ __launch_bounds__(256) void qkv_part(
        const float* __restrict__ h,
        const float* __restrict__ Wq, const float* __restrict__ Wk,
        const float* __restrict__ Wv,
        float* __restrict__ part, int n, int pool_s, int S) {
    int z = blockIdx.z;
    int which = z / S, s = z % S;
    const float* W = (which == 0) ? Wq : ((which == 1) ? Wk : Wv);
    int kq = DD / S;
    gemm_part_body(h, DD, pool_s, W, QKVN,
                   part + ((size_t)which * S + s) * n * QKVN,
                   n, QKVN, s * kq, s * kq + kq);
}

// ---------- reduce epilogues ----------
__global__ void reduce_bias(const float* __restrict__ part,
                            const float* __restrict__ bias,
                            float* __restrict__ out,
                            int MN, int N, int S, int act) {
    int i = blockIdx.x * 256 + threadIdx.x;
    if (i >= MN) return;
    float v = 0.f;
    for (int s = 0; s < S; ++s) v += part[(size_t)s * MN + i];
    v += bias[i % N];
    if (act) v = gelu_exact(v);
    out[i] = v;
}

__global__ void qkv_reduce(const float* __restrict__ part,
                           const float* __restrict__ bq,
                           const float* __restrict__ bk,
                           const float* __restrict__ bv,
                           float* __restrict__ qkv, int n, int S) {
    int i = blockIdx.x * 256 + threadIdx.x;
    if (i >= 3 * n * QKVN) return;
    int which = i / (n * QKVN);
    int r = i - which * n * QKVN;
    int m = r / QKVN, c = r - m * QKVN;
    float v = 0.f;
    for (int s = 0; s < S; ++s) v += part[((size_t)which * S + s) * n * QKVN + r];
    v += (which == 0 ? bq : (which == 1 ? bk : bv))[c];
    qkv[(size_t)m * QKV3 + which * QKVN + c] = v;
}

// ---------- comb A gather: [500][1536] = concat(a0, rep(a1), rep(a2)) ----------
__global__ void comb_gather(const float* __restrict__ a0, const float* __restrict__ a1,
                            const float* __restrict__ a2, float* __restrict__ combA) {
    int i = blockIdx.x * 256 + threadIdx.x;
    if (i >= NN * 3 * DD) return;
    int row = i / (3 * DD), c = i - row * 3 * DD;
    int si = c >> 9, cc = c & (DD - 1);
    const float* ap = (si == 0) ? a0 : ((si == 1) ? a1 : a2);
    combA[i] = ap[(size_t)(row >> si) * DD + cc];
}

// ---------- attention ----------
__global__ void scores_kernel(const float* __restrict__ qkv, float* __restrict__ sc, int n) {
    size_t idx = (size_t)blockIdx.x * 256 + threadIdx.x;
    size_t tot = (size_t)HSC * n * n;
    if (idx >= tot) return;
    int j = (int)(idx % n);
    size_t t = idx / n;
    int i = (int)(t % n);
    int h = (int)(t / n);
    const float* qp = qkv + (size_t)i * QKV3 + h * KDD;
    const float* kp = qkv + (size_t)j * QKV3 + QKVN + h * KDD;
    float acc = 0.f;
    #pragma unroll
    for (int c = 0; c < KDD; ++c) acc += qp[c] * kp[c];
    sc[idx] = acc * 0.17677669529663687f;  // 1/sqrt(32)
}

__global__ void softmax_rows(float* __restrict__ sc, int n) {
    int row = blockIdx.x;
    float* p = sc + (size_t)row * n;
    int t = threadIdx.x;
    int lane = t & 63, wv = t >> 6;
    __shared__ float r[4];
    __shared__ float bmx, bsum;
    float mx = -1e30f;
    for (int j = t; j < n; j += 256) mx = fmaxf(mx, p[j]);
    for (int off = 32; off; off >>= 1) mx = fmaxf(mx, __shfl_down(mx, off));
    if (lane == 0) r[wv] = mx;
    __syncthreads();
    if (t == 0) bmx = fmaxf(fmaxf(r[0], r[1]), fmaxf(r[2], r[3]));
    __syncthreads();
    float m = bmx;
    float s = 0.f;
    for (int j = t; j < n; j += 256) {
        float e = expf(p[j] - m);
        p[j] = e;
        s += e;
    }
    for (int off = 32; off; off >>= 1) s += __shfl_down(s, off);
    if (lane == 0) r[wv] = s;
    __syncthreads();
    if (t == 0) bsum = 1.f / (r[0] + r[1] + r[2] + r[3]);
    __syncthreads();
    float inv = bsum;
    for (int j = t; j < n; j += 256) p[j] *= inv;
}

__global__ void attn_o(const float* __restrict__ p, const float* __restrict__ qkv,
                       float* __restrict__ o, int n) {
    int idx = blockIdx.x * 256 + threadIdx.x;
    if (idx >= n * QKVN) return;
    int hk = idx % QKVN;
    int i = idx / QKVN;
    int h = hk >> 5;
    const float* pr = p + (size_t)h * n * n + (size_t)i * n;
    const float* vb = qkv + 2 * QKVN + hk;
    float a0 = 0.f, a1 = 0.f, a2 = 0.f, a3 = 0.f;
    int j = 0;
    for (; j + 3 < n; j += 4) {
        a0 += pr[j]     * vb[(size_t)j * QKV3];
        a1 += pr[j + 1] * vb[(size_t)(j + 1) * QKV3];
        a2 += pr[j + 2] * vb[(size_t)(j + 2) * QKV3];
        a3 += pr[j + 3] * vb[(size_t)(j + 3) * QKV3];
    }
    for (; j < n; ++j) a0 += pr[j] * vb[(size_t)j * QKV3];
    o[idx] = (a0 + a1) + (a2 + a3);
}

// ---------- h = LayerNorm(h + delta) * g + b ----------
__global__ void add_ln(float* __restrict__ h, const float* __restrict__ delta,
                       const float* __restrict__ gw, const float* __restrict__ bw) {
    int n = blockIdx.x;
    int t = threadIdx.x;  // 512
    float x = h[(size_t)n * DD + t] + delta[(size_t)n * DD + t];
    int lane = t & 63, wv = t >> 6;
    __shared__ float s1[8], s2[8];
    __shared__ float mb[2];
    float sum = x, sq = x * x;
    for (int off = 32; off; off >>= 1) {
        sum += __shfl_down(sum, off);
        sq  += __shfl_down(sq,  off);
    }
    if (lane == 0) { s1[wv] = sum; s2[wv] = sq; }
    __syncthreads();
    if (t == 0) {
        float a = 0.f, b = 0.f;
        for (int i = 0; i < 8; ++i) { a += s1[i]; b += s2[i]; }
        float mean = a / (float)DD;
        float var = b / (float)DD - mean * mean;
        mb[0] = mean;
        mb[1] = rsqrtf(var + LNEPS);
    }
    __syncthreads();
    h[(size_t)n * DD + t] = (x - mb[0]) * mb[1] * gw[t] + bw[t];
}

// ---------- head ----------
__global__ void head_kernel(const float* __restrict__ h, const float* __restrict__ hw,
                            const float* __restrict__ hb, float* __restrict__ out) {
    __shared__ float gs[DD];
    __shared__ float r[4];
    __shared__ float bmx, bsum;
    int t = threadIdx.x;  // 256
    for (int d = t; d < DD; d += 256) {
        float s = 0.f;
        for (int n = 0; n < NN; ++n) s += h[(size_t)n * DD + d];
        gs[d] = s / (float)NN;
    }
    __syncthreads();
    float acc = hb[t];
    for (int d = 0; d < DD; ++d) acc += gs[d] * hw[(size_t)d * NC + t];
    int lane = t & 63, wv = t >> 6;
    float mx = acc;
    for (int off = 32; off; off >>= 1) mx = fmaxf(mx, __shfl_down(mx, off));
    if (lane == 0) r[wv] = mx;
    __syncthreads();
    if (t == 0) bmx = fmaxf(fmaxf(r[0], r[1]), fmaxf(r[2], r[3]));
    __syncthreads();
    float e = expf(acc - bmx);
    float s = e;
    for (int off = 32; off; off >>= 1) s += __shfl_down(s, off);
    if (lane == 0) r[wv] = s;
    __syncthreads();
    if (t == 0) bsum = 1.f / (r[0] + r[1] + r[2] + r[3]);
    __syncthreads();
    float pv = e * bsum;
    for (int b = 0; b < NB; ++b) out[(size_t)b * NC + t] = pv;
}

extern "C" void kernel_launch(void* const* d_in, const int* in_sizes, int n_in,
                              void* d_out, int out_size, void* d_ws, size_t ws_size,
                              hipStream_t stream) {
    const float* ln_in_b = (const float*)d_in[2];
    const float* patch_W = (const float*)d_in[3];
    const float* patch_b = (const float*)d_in[4];
    const float* pos_emb = (const float*)d_in[5];
    const float* Wq = (const float*)d_in[6];
    const float* bq = (const float*)d_in[7];
    const float* Wk = (const float*)d_in[8];
    const float* bk = (const float*)d_in[9];
    const float* Wv = (const float*)d_in[10];
    const float* bv = (const float*)d_in[11];
    const float* Wo = (const float*)d_in[12];
    const float* bo = (const float*)d_in[13];
    const float* Wc = (const float*)d_in[14];
    const float* bc = (const float*)d_in[15];
    const float* ln1_g = (const float*)d_in[16];
    const float* ln1_b = (const float*)d_in[17];
    const float* W1 = (const float*)d_in[18];
    const float* b1 = (const float*)d_in[19];
    const float* W2 = (const float*)d_in[20];
    const float* b2 = (const float*)d_in[21];
    const float* ln2_g = (const float*)d_in[22];
    const float* ln2_b = (const float*)d_in[23];
    const float* head_W = (const float*)d_in[24];
    const float* head_b = (const float*)d_in[25];
    float* out = (float*)d_out;

    // workspace layout (floats), ~25.5 MB
    float* ws = (float*)d_ws;
    float* h     = ws;                 // 256000
    float* csum  = h + 256000;         // 512 (+pad)
    float* qkv   = csum + 1024;        // 240000
    float* sc    = qkv + 240000;       // 1250000
    float* o     = sc + 1250000;       // 80000
    float* a0    = o + 80000;          // 256000
    float* a1    = a0 + 256000;        // 128000
    float* a2    = a1 + 128000;        // 64000
    float* combA = a2 + 64000;         // 768000
    float* tmp   = combA + 768000;     // 256000
    float* f     = tmp + 256000;       // 1024000
    float* part  = f + 1024000;        // 2048000 max

    colsum_kernel<<<1, 512, 0, stream>>>(patch_W, csum);
    init_h<<<(NN * DD + 255) / 256, 256, 0, stream>>>(csum, patch_b, pos_emb, ln_in_b, h);

    static const int scales_[3] = {1, 2, 4};
    float* aouts[3] = {a0, a1, a2};

    for (int l = 0; l < NL; ++l) {
        for (int si = 0; si < 3; ++si) {
            int s = scales_[si];
            int n = NN / s;
            size_t w = (size_t)(l * 3 + si);
            int Mt = (n + BM - 1) / BM;

            // QKV: K=512, S=8 (kq=64); grid z = 3*8
            {
                const int S = 8;
                dim3 g((QKVN + BN - 1) / BN, Mt, 3 * S);
                qkv_part<<<g, 256, 0, stream>>>(
                    h, Wq + w * DD * QKVN, Wk + w * DD * QKVN, Wv + w * DD * QKVN,
                    part, n, s, S);
                qkv_reduce<<<(3 * n * QKVN + 255) / 256, 256, 0, stream>>>(
                    part, bq + w * QKVN, bk + w * QKVN, bv + w * QKVN, qkv, n, S);
            }
            size_t tsc = (size_t)HSC * n * n;
            scores_kernel<<<(unsigned)((tsc + 255) / 256), 256, 0, stream>>>(qkv, sc, n);
            softmax_rows<<<HSC * n, 256, 0, stream>>>(sc, n);
            attn_o<<<(n * QKVN + 255) / 256, 256, 0, stream>>>(sc, qkv, o, n);
            // Wo: K=160, S=5 (kq=32)
            {
                const int S = 5;
                dim3 g(DD / BN, Mt, S);
                gemm_part<<<g, 256, 0, stream>>>(o, QKVN, 1, Wo + w * QKVN * DD, DD,
                                                 part, n, DD, QKVN, S);
                reduce_bias<<<(n * DD + 255) / 256, 256, 0, stream>>>(
                    part, bo + w * DD, aouts[si], n * DD, DD, S, 0);
            }
        }
        // comb: K=1536, S=8 (kq=192)
        comb_gather<<<(NN * 3 * DD + 255) / 256, 256, 0, stream>>>(a0, a1, a2, combA);
        {
            const int S = 8;
            dim3 g(DD / BN, (NN + BM - 1) / BM, S);
            gemm_part<<<g, 256, 0, stream>>>(combA, 3 * DD, 1,
                                             Wc + (size_t)l * 3 * DD * DD, DD,
                                             part, NN, DD, 3 * DD, S);
            reduce_bias<<<(NN * DD + 255) / 256, 256, 0, stream>>>(
                part, bc + (size_t)l * DD, tmp, NN * DD, DD, S, 0);
        }
        add_ln<<<NN, DD, 0, stream>>>(h, tmp, ln1_g + (size_t)l * DD, ln1_b + (size_t)l * DD);
        // W1: K=512, S=2 (kq=256), gelu in reduce
        {
            const int S = 2;
            dim3 g(FF / BN, (NN + BM - 1) / BM, S);
            gemm_part<<<g, 256, 0, stream>>>(h, DD, 1, W1 + (size_t)l * DD * FF, FF,
                                             part, NN, FF, DD, S);
            reduce_bias<<<(NN * FF + 255) / 256, 256, 0, stream>>>(
                part, b1 + (size_t)l * FF, f, NN * FF, FF, S, 1);
        }
        // W2: K=2048, S=8 (kq=256)
        {
            const int S = 8;
            dim3 g(DD / BN, (NN + BM - 1) / BM, S);
            gemm_part<<<g, 256, 0, stream>>>(f, FF, 1, W2 + (size_t)l * FF * DD, DD,
                                             part, NN, DD, FF, S);
            reduce_bias<<<(NN * DD + 255) / 256, 256, 0, stream>>>(
                part, b2 + (size_t)l * DD, tmp, NN * DD, DD, S, 0);
        }
        add_ln<<<NN, DD, 0, stream>>>(h, tmp, ln2_g + (size_t)l * DD, ln2_b + (size_t)l * DD);
    }
    head_kernel<<<1, 256, 0, stream>>>(h, head_W, head_b, out);
}

// Round 4
// 1612.640 us; speedup vs baseline: 4.6154x; 1.2944x over previous
//
#include <hip/hip_runtime.h>
#include <math.h>

// Model constants: B=32, T=50000, P=100, D=512, H=16, L=6, C=256
// SCALES=[1,2,4], HS=5 heads/scale, KD=32, N=500 patches, FF=2048, EPS=1e-3.
//
// KEY INSIGHT (round 0, verified): first layernorm is over a size-1 axis ->
// output == ln_in_b[0] everywhere. h is batch-independent; network runs once
// on (500 x 512); final row broadcast x32.
//
// Round 4: launch-count attack. 183 -> 52 launches (8/layer):
//   qkv_all (3 scales, pool+bias fused) | attn_fused (flash-style, kills
//   scores/softmax/attn_o) | wo_all (3 scales) | comb_part (gather in A-stage)
//   | reduce+add+LN fused | W1 single (bias+gelu fused) | W2 split-K |
//   reduce+add+LN fused. head_kernel parallelized (was 58us on 1 block).

#define DD 512
#define NN 500
#define HSC 5
#define KDD 32
#define QKVN 160
#define QKV3 480
#define FF 2048
#define NL 6
#define NC 256
#define NB 32
#define LNEPS 1e-3f
#define BM 128
#define BN 64
#define KCH 32

// contiguous sub-buffer offsets (floats)
#define AOFF1 256000
#define AOFF2 384000

__device__ __forceinline__ float gelu_exact(float x) {
    return 0.5f * x * (1.0f + erff(x * 0.70710678118654752f));
}

// ======================= GEMM core =======================
// acc[8][4] += A(M x ks..kend)@B ; A optionally pooled (pool_s rows avg) or
// comb-gathered (a0/a1/a2 concat with row>>si repeat). BM=128 x BN=64, KC=32.
__device__ __forceinline__ void gc_stage(
        const float* __restrict__ A, int lda, int pool_s, float inv_pool, int gather,
        const float* __restrict__ B, int ldb,
        int M, int N, int bm, int bn, int k0,
        int am, int akv, int bk, int bn4, float4* aR, float4* bR) {
    if (!gather) {
        #pragma unroll
        for (int p = 0; p < 4; ++p) {
            int row = bm + p * 32 + am;
            float4 v = make_float4(0.f, 0.f, 0.f, 0.f);
            if (row < M) {
                const float* ap = A + (size_t)row * pool_s * lda + k0 + akv * 4;
                v = *(const float4*)ap;
                for (int t = 1; t < pool_s; ++t) {
                    float4 u = *(const float4*)(ap + (size_t)t * lda);
                    v.x += u.x; v.y += u.y; v.z += u.z; v.w += u.w;
                }
                v.x *= inv_pool; v.y *= inv_pool; v.z *= inv_pool; v.w *= inv_pool;
            }
            aR[p] = v;
        }
    } else {
        int si = k0 >> 9;
        int dd0 = k0 & (DD - 1);
        const float* ap0 = A + (si == 0 ? 0 : (si == 1 ? AOFF1 : AOFF2));
        #pragma unroll
        for (int p = 0; p < 4; ++p) {
            int row = bm + p * 32 + am;
            float4 v = make_float4(0.f, 0.f, 0.f, 0.f);
            if (row < M)
                v = *(const float4*)(ap0 + (size_t)(row >> si) * DD + dd0 + akv * 4);
            aR[p] = v;
        }
    }
    int col = bn + bn4 * 4;
    #pragma unroll
    for (int p = 0; p < 2; ++p) {
        int kk = p * 16 + bk;
        float4 v = make_float4(0.f, 0.f, 0.f, 0.f);
        if (col < N) v = *(const float4*)(B + (size_t)(k0 + kk) * ldb + col);
        bR[p] = v;
    }
}

__device__ __forceinline__ void gemm_core(
        const float* __restrict__ A, int lda, int pool_s, int gather,
        const float* __restrict__ B, int ldb,
        int M, int N, int bm, int bn, int ks, int kend,
        float (&acc)[8][4]) {
    __shared__ float As[KCH][132];
    __shared__ float Bs[KCH][68];
    int tid = threadIdx.x;
    int am = tid >> 3, akv = tid & 7;
    int bk = tid >> 4, bn4 = tid & 15;
    float inv_pool = 1.0f / (float)pool_s;

    float4 aR[4], bR[2];
    gc_stage(A, lda, pool_s, inv_pool, gather, B, ldb, M, N, bm, bn, ks,
             am, akv, bk, bn4, aR, bR);
    int nch = (kend - ks) / KCH;
    int tx = tid & 15, ty = tid >> 4;
    for (int c = 0; c < nch; ++c) {
        __syncthreads();
        #pragma unroll
        for (int p = 0; p < 4; ++p) {
            int m = p * 32 + am;
            As[akv * 4 + 0][m] = aR[p].x;
            As[akv * 4 + 1][m] = aR[p].y;
            As[akv * 4 + 2][m] = aR[p].z;
            As[akv * 4 + 3][m] = aR[p].w;
        }
        #pragma unroll
        for (int p = 0; p < 2; ++p)
            *(float4*)&Bs[p * 16 + bk][bn4 * 4] = bR[p];
        __syncthreads();
        if (c + 1 < nch)
            gc_stage(A, lda, pool_s, inv_pool, gather, B, ldb, M, N, bm, bn,
                     ks + (c + 1) * KCH, am, akv, bk, bn4, aR, bR);
        #pragma unroll
        for (int kk = 0; kk < KCH; ++kk) {
            float4 b  = *(const float4*)&Bs[kk][tx * 4];
            float4 al = *(const float4*)&As[kk][ty * 8];
            float4 ah = *(const float4*)&As[kk][ty * 8 + 4];
            float a8[8] = {al.x, al.y, al.z, al.w, ah.x, ah.y, ah.z, ah.w};
            float b4[4] = {b.x, b.y, b.z, b.w};
            #pragma unroll
            for (int u = 0; u < 8; ++u)
                #pragma unroll
                for (int v = 0; v < 4; ++v)
                    acc[u][v] += a8[u] * b4[v];
        }
    }
}

#define ACC_INIT(acc) { _Pragma("unroll") for (int u=0;u<8;++u) _Pragma("unroll") for (int v=0;v<4;++v) acc[u][v]=0.f; }

// ======================= setup =======================
__global__ void colsum_kernel(const float* __restrict__ pw, float* __restrict__ csum) {
    int d = blockIdx.x * blockDim.x + threadIdx.x;
    if (d < DD) {
        float s = 0.f;
        for (int p = 0; p < 100; ++p) s += pw[p * DD + d];
        csum[d] = s;
    }
}

__global__ void init_h(const float* __restrict__ csum, const float* __restrict__ pb,
                       const float* __restrict__ pos, const float* __restrict__ lnb,
                       float* __restrict__ h) {
    int idx = blockIdx.x * 256 + threadIdx.x;
    if (idx >= NN * DD) return;
    int d = idx & (DD - 1);
    h[idx] = lnb[0] * csum[d] + pb[d] + pos[idx];
}

// ======================= QKV (all scales, one launch) =======================
// grid (9, 4, 3): x = which*3 + coltile, y = row tile, z = scale
__global__ __launch_bounds__(256) void qkv_all(
        const float* __restrict__ h,
        const float* __restrict__ Wq, const float* __restrict__ bq,
        const float* __restrict__ Wk, const float* __restrict__ bk,
        const float* __restrict__ Wv, const float* __restrict__ bv,
        float* __restrict__ qkvAll, int l) {
    int z = blockIdx.z;
    int n = NN >> z;
    int pool_s = 1 << z;
    if ((int)blockIdx.y * BM >= n) return;
    int which = blockIdx.x / 3;
    int bn = (blockIdx.x % 3) * BN;
    int bm = blockIdx.y * BM;
    size_t w = (size_t)(l * 3 + z);
    const float* W = (which == 0) ? Wq : ((which == 1) ? Wk : Wv);
    const float* bias = ((which == 0) ? bq : ((which == 1) ? bk : bv)) + w * QKVN;
    float* outb = qkvAll + (z == 0 ? 0 : (z == 1 ? 240000 : 360000));

    float acc[8][4];
    ACC_INIT(acc);
    gemm_core(h, DD, pool_s, 0, W + w * DD * QKVN, QKVN, n, QKVN, bm, bn, 0, DD, acc);

    int tid = threadIdx.x, tx = tid & 15, ty = tid >> 4;
    int col = bn + tx * 4;
    if (col < QKVN) {
        #pragma unroll
        for (int u = 0; u < 8; ++u) {
            int row = bm + ty * 8 + u;
            if (row < n) {
                float4 o;
                o.x = acc[u][0] + bias[col];
                o.y = acc[u][1] + bias[col + 1];
                o.z = acc[u][2] + bias[col + 2];
                o.w = acc[u][3] + bias[col + 3];
                *(float4*)&outb[(size_t)row * QKV3 + which * QKVN + col] = o;
            }
        }
    }
}

// ======================= fused attention =======================
// grid (8, 5, 3): x = 64-query tile, y = head, z = scale. 256 threads:
// kg = tid&3 (key quarter), qi = tid>>2 (query). Online softmax, K/V in LDS.
__global__ __launch_bounds__(256) void attn_fused(
        const float* __restrict__ qkvAll, float* __restrict__ oAll) {
    int z = blockIdx.z;
    int n = NN >> z;
    int qt = blockIdx.x, hh = blockIdx.y;
    if (qt * 64 >= n) return;
    const float* qkv = qkvAll + (z == 0 ? 0 : (z == 1 ? 240000 : 360000));
    float* ob = oAll + (z == 0 ? 0 : (z == 1 ? 80000 : 120000));
    int tid = threadIdx.x;
    int kg = tid & 3, qi = tid >> 2;
    int qrow = qt * 64 + qi;
    bool qok = qrow < n;

    float qreg[32];
    {
        const float* qp = qkv + (size_t)(qok ? qrow : 0) * QKV3 + hh * KDD;
        #pragma unroll
        for (int c4 = 0; c4 < 8; ++c4) {
            float4 v = qok ? *(const float4*)(qp + c4 * 4) : make_float4(0.f, 0.f, 0.f, 0.f);
            qreg[c4 * 4 + 0] = v.x; qreg[c4 * 4 + 1] = v.y;
            qreg[c4 * 4 + 2] = v.z; qreg[c4 * 4 + 3] = v.w;
        }
    }
    __shared__ float Ks[64][33];
    __shared__ float Vs[64][33];
    float o[32];
    #pragma unroll
    for (int c = 0; c < 32; ++c) o[c] = 0.f;
    float m = -1e30f, l = 0.f;
    int nkc = (n + 63) >> 6;
    int sr = tid & 63, sc4 = tid >> 6;  // staging: 4 threads/row

    for (int kc = 0; kc < nkc; ++kc) {
        __syncthreads();
        int krow = kc * 64 + sr;
        bool ok = krow < n;
        const float* kp = qkv + (size_t)(ok ? krow : 0) * QKV3 + QKVN + hh * KDD;
        const float* vp = kp + QKVN;
        #pragma unroll
        for (int half = 0; half < 2; ++half) {
            int cc = (half * 4 + sc4) * 4;
            float4 kv = ok ? *(const float4*)(kp + cc) : make_float4(0.f, 0.f, 0.f, 0.f);
            float4 vv = ok ? *(const float4*)(vp + cc) : make_float4(0.f, 0.f, 0.f, 0.f);
            Ks[sr][cc + 0] = kv.x; Ks[sr][cc + 1] = kv.y; Ks[sr][cc + 2] = kv.z; Ks[sr][cc + 3] = kv.w;
            Vs[sr][cc + 0] = vv.x; Vs[sr][cc + 1] = vv.y; Vs[sr][cc + 2] = vv.z; Vs[sr][cc + 3] = vv.w;
        }
        __syncthreads();
        float p[16];
        float cmax = -1e30f;
        #pragma unroll
        for (int jj = 0; jj < 16; ++jj) {
            int j = kg * 16 + jj;
            float s = 0.f;
            #pragma unroll
            for (int c4 = 0; c4 < 8; ++c4) {
                float4 kv = *(const float4*)&Ks[j][c4 * 4];
                s += qreg[c4 * 4] * kv.x + qreg[c4 * 4 + 1] * kv.y
                   + qreg[c4 * 4 + 2] * kv.z + qreg[c4 * 4 + 3] * kv.w;
            }
            s *= 0.17677669529663687f;
            if (kc * 64 + j >= n) s = -1e30f;
            p[jj] = s;
            cmax = fmaxf(cmax, s);
        }
        cmax = fmaxf(cmax, __shfl_xor(cmax, 1));
        cmax = fmaxf(cmax, __shfl_xor(cmax, 2));
        float mnew = fmaxf(m, cmax);
        float alpha = expf(m - mnew);
        m = mnew;
        float ls = 0.f;
        #pragma unroll
        for (int jj = 0; jj < 16; ++jj) {
            p[jj] = expf(p[jj] - mnew);
            ls += p[jj];
        }
        l = l * alpha + ls;
        #pragma unroll
        for (int c = 0; c < 32; ++c) o[c] *= alpha;
        #pragma unroll
        for (int jj = 0; jj < 16; ++jj) {
            int j = kg * 16 + jj;
            float pj = p[jj];
            #pragma unroll
            for (int c4 = 0; c4 < 8; ++c4) {
                float4 vv = *(const float4*)&Vs[j][c4 * 4];
                o[c4 * 4 + 0] += pj * vv.x; o[c4 * 4 + 1] += pj * vv.y;
                o[c4 * 4 + 2] += pj * vv.z; o[c4 * 4 + 3] += pj * vv.w;
            }
        }
    }
    l += __shfl_xor(l, 1);
    l += __shfl_xor(l, 2);
    #pragma unroll
    for (int c = 0; c < 32; ++c) {
        o[c] += __shfl_xor(o[c], 1);
        o[c] += __shfl_xor(o[c], 2);
    }
    if (qok && kg == 0) {
        float inv = 1.f / l;
        float* op = ob + (size_t)qrow * QKVN + hh * KDD;
        #pragma unroll
        for (int c4 = 0; c4 < 8; ++c4) {
            float4 v;
            v.x = o[c4 * 4 + 0] * inv; v.y = o[c4 * 4 + 1] * inv;
            v.z = o[c4 * 4 + 2] * inv; v.w = o[c4 * 4 + 3] * inv;
            *(float4*)(op + c4 * 4) = v;
        }
    }
}

// ======================= Wo (all scales, bias fused) =======================
// grid (8, 4, 3)
__global__ __launch_bounds__(256) void wo_all(
        const float* __restrict__ oAll, const float* __restrict__ Wo,
        const float* __restrict__ bo, float* __restrict__ aAll, int l) {
    int z = blockIdx.z;
    int n = NN >> z;
    if ((int)blockIdx.y * BM >= n) return;
    int bm = blockIdx.y * BM, bn = blockIdx.x * BN;
    size_t w = (size_t)(l * 3 + z);
    const float* A = oAll + (z == 0 ? 0 : (z == 1 ? 80000 : 120000));
    float* C = aAll + (z == 0 ? 0 : (z == 1 ? AOFF1 : AOFF2));
    const float* bias = bo + w * DD;

    float acc[8][4];
    ACC_INIT(acc);
    gemm_core(A, QKVN, 1, 0, Wo + w * QKVN * DD, DD, n, DD, bm, bn, 0, QKVN, acc);

    int tid = threadIdx.x, tx = tid & 15, ty = tid >> 4;
    int col = bn + tx * 4;
    #pragma unroll
    for (int u = 0; u < 8; ++u) {
        int row = bm + ty * 8 + u;
        if (row < n) {
            float4 o;
            o.x = acc[u][0] + bias[col];     o.y = acc[u][1] + bias[col + 1];
            o.z = acc[u][2] + bias[col + 2]; o.w = acc[u][3] + bias[col + 3];
            *(float4*)&C[(size_t)row * DD + col] = o;
        }
    }
}

// ======================= comb partial (gather-A) =======================
// grid (8, 4, 6): kq = 256
__global__ __launch_bounds__(256) void comb_part(
        const float* __restrict__ aAll, const float* __restrict__ Wc,
        float* __restrict__ part) {
    int zz = blockIdx.z;
    int bm = blockIdx.y * BM, bn = blockIdx.x * BN;
    float acc[8][4];
    ACC_INIT(acc);
    gemm_core(aAll, DD, 1, 1, Wc, DD, NN, DD, bm, bn, zz * 256, zz * 256 + 256, acc);
    float* pz = part + (size_t)zz * NN * DD;
    int tid = threadIdx.x, tx = tid & 15, ty = tid >> 4;
    int col = bn + tx * 4;
    #pragma unroll
    for (int u = 0; u < 8; ++u) {
        int row = bm + ty * 8 + u;
        if (row < NN) {
            float4 o;
            o.x = acc[u][0]; o.y = acc[u][1]; o.z = acc[u][2]; o.w = acc[u][3];
            *(float4*)&pz[(size_t)row * DD + col] = o;
        }
    }
}

// ======================= W1 direct (bias+gelu) =======================
// grid (32, 4)
__global__ __launch_bounds__(256) void w1_direct(
        const float* __restrict__ h, const float* __restrict__ W1,
        const float* __restrict__ b1, float* __restrict__ f) {
    int bm = blockIdx.y * BM, bn = blockIdx.x * BN;
    float acc[8][4];
    ACC_INIT(acc);
    gemm_core(h, DD, 1, 0, W1, FF, NN, FF, bm, bn, 0, DD, acc);
    int tid = threadIdx.x, tx = tid & 15, ty = tid >> 4;
    int col = bn + tx * 4;
    #pragma unroll
    for (int u = 0; u < 8; ++u) {
        int row = bm + ty * 8 + u;
        if (row < NN) {
            float4 o;
            o.x = gelu_exact(acc[u][0] + b1[col]);
            o.y = gelu_exact(acc[u][1] + b1[col + 1]);
            o.z = gelu_exact(acc[u][2] + b1[col + 2]);
            o.w = gelu_exact(acc[u][3] + b1[col + 3]);
            *(float4*)&f[(size_t)row * FF + col] = o;
        }
    }
}

// ======================= W2 partial =======================
// grid (8, 4, 8): kq = 256
__global__ __launch_bounds__(256) void w2_part(
        const float* __restrict__ f, const float* __restrict__ W2,
        float* __restrict__ part) {
    int zz = blockIdx.z;
    int bm = blockIdx.y * BM, bn = blockIdx.x * BN;
    float acc[8][4];
    ACC_INIT(acc);
    gemm_core(f, FF, 1, 0, W2, DD, NN, DD, bm, bn, zz * 256, zz * 256 + 256, acc);
    float* pz = part + (size_t)zz * NN * DD;
    int tid = threadIdx.x, tx = tid & 15, ty = tid >> 4;
    int col = bn + tx * 4;
    #pragma unroll
    for (int u = 0; u < 8; ++u) {
        int row = bm + ty * 8 + u;
        if (row < NN) {
            float4 o;
            o.x = acc[u][0]; o.y = acc[u][1]; o.z = acc[u][2]; o.w = acc[u][3];
            *(float4*)&pz[(size_t)row * DD + col] = o;
        }
    }
}

// ======================= fused reduce + bias + residual + LN =======================
// grid (500), 512 threads
__global__ void reduce_add_ln(const float* __restrict__ part, int S,
                              const float* __restrict__ bias,
                              float* __restrict__ h,
                              const float* __restrict__ gw,
                              const float* __restrict__ bw) {
    int row = blockIdx.x, t = threadIdx.x;
    size_t idx = (size_t)row * DD + t;
    float x = h[idx] + bias[t];
    for (int s = 0; s < S; ++s) x += part[(size_t)s * NN * DD + idx];
    int lane = t & 63, wv = t >> 6;
    __shared__ float s1[8], s2[8];
    __shared__ float mb[2];
    float sum = x, sq = x * x;
    for (int off = 32; off; off >>= 1) {
        sum += __shfl_down(sum, off);
        sq  += __shfl_down(sq,  off);
    }
    if (lane == 0) { s1[wv] = sum; s2[wv] = sq; }
    __syncthreads();
    if (t == 0) {
        float a = 0.f, b = 0.f;
        for (int i = 0; i < 8; ++i) { a += s1[i]; b += s2[i]; }
        float mean = a / (float)DD;
        float var = b / (float)DD - mean * mean;
        mb[0] = mean;
        mb[1] = rsqrtf(var + LNEPS);
    }
    __syncthreads();
    h[idx] = (x - mb[0]) * mb[1] * gw[t] + bw[t];
}

// ======================= head =======================
// stage 1: grid (2, 25), 256 thr: partial[by][col] = sum of 20 rows
__global__ void col_mean_part(const float* __restrict__ h, float* __restrict__ partial) {
    int col = blockIdx.x * 256 + threadIdx.x;
    int r0 = blockIdx.y * 20;
    float s = 0.f;
    #pragma unroll
    for (int r = 0; r < 20; ++r) s += h[(size_t)(r0 + r) * DD + col];
    partial[(size_t)blockIdx.y * DD + col] = s;
}

// stage 2: one block, 256 threads (one per class)
__global__ void head_kernel(const float* __restrict__ partial,
                            const float* __restrict__ hw,
                            const float* __restrict__ hb, float* __restrict__ out) {
    __shared__ float gs[DD];
    __shared__ float r[4];
    __shared__ float bmx, bsum;
    int t = threadIdx.x;
    for (int d = t; d < DD; d += 256) {
        float s = 0.f;
        #pragma unroll
        for (int p = 0; p < 25; ++p) s += partial[(size_t)p * DD + d];
        gs[d] = s / (float)NN;
    }
    __syncthreads();
    float acc = hb[t];
    #pragma unroll 16
    for (int d = 0; d < DD; ++d) acc += gs[d] * hw[(size_t)d * NC + t];
    int lane = t & 63, wv = t >> 6;
    float mx = acc;
    for (int off = 32; off; off >>= 1) mx = fmaxf(mx, __shfl_down(mx, off));
    if (lane == 0) r[wv] = mx;
    __syncthreads();
    if (t == 0) bmx = fmaxf(fmaxf(r[0], r[1]), fmaxf(r[2], r[3]));
    __syncthreads();
    float e = expf(acc - bmx);
    float s = e;
    for (int off = 32; off; off >>= 1) s += __shfl_down(s, off);
    if (lane == 0) r[wv] = s;
    __syncthreads();
    if (t == 0) bsum = 1.f / (r[0] + r[1] + r[2] + r[3]);
    __syncthreads();
    float pv = e * bsum;
    for (int b = 0; b < NB; ++b) out[(size_t)b * NC + t] = pv;
}

extern "C" void kernel_launch(void* const* d_in, const int* in_sizes, int n_in,
                              void* d_out, int out_size, void* d_ws, size_t ws_size,
                              hipStream_t stream) {
    const float* ln_in_b = (const float*)d_in[2];
    const float* patch_W = (const float*)d_in[3];
    const float* patch_b = (const float*)d_in[4];
    const float* pos_emb = (const float*)d_in[5];
    const float* Wq = (const float*)d_in[6];
    const float* bq = (const float*)d_in[7];
    const float* Wk = (const float*)d_in[8];
    const float* bk = (const float*)d_in[9];
    const float* Wv = (const float*)d_in[10];
    const float* bv = (const float*)d_in[11];
    const float* Wo = (const float*)d_in[12];
    const float* bo = (const float*)d_in[13];
    const float* Wc = (const float*)d_in[14];
    const float* bc = (const float*)d_in[15];
    const float* ln1_g = (const float*)d_in[16];
    const float* ln1_b = (const float*)d_in[17];
    const float* W1 = (const float*)d_in[18];
    const float* b1 = (const float*)d_in[19];
    const float* W2 = (const float*)d_in[20];
    const float* b2 = (const float*)d_in[21];
    const float* ln2_g = (const float*)d_in[22];
    const float* ln2_b = (const float*)d_in[23];
    const float* head_W = (const float*)d_in[24];
    const float* head_b = (const float*)d_in[25];
    float* out = (float*)d_out;

    // workspace (floats) ~17.5 MB
    float* ws = (float*)d_ws;
    float* h      = ws;                  // 256000
    float* csum   = h + 256000;          // 1024
    float* qkvAll = csum + 1024;         // 420000 (500+250+125)*480
    float* oAll   = qkvAll + 420000;     // 140000 (500+250+125)*160
    float* aAll   = oAll + 140000;       // 448000 (a0|a1|a2)
    float* f      = aAll + 448000;       // 1024000
    float* part   = f + 1024000;         // 2048000 (max S=8)
    float* headp  = part + 2048000;      // 12800

    colsum_kernel<<<1, 512, 0, stream>>>(patch_W, csum);
    init_h<<<(NN * DD + 255) / 256, 256, 0, stream>>>(csum, patch_b, pos_emb, ln_in_b, h);

    for (int l = 0; l < NL; ++l) {
        qkv_all<<<dim3(9, 4, 3), 256, 0, stream>>>(h, Wq, bq, Wk, bk, Wv, bv, qkvAll, l);
        attn_fused<<<dim3(8, HSC, 3), 256, 0, stream>>>(qkvAll, oAll);
        wo_all<<<dim3(8, 4, 3), 256, 0, stream>>>(oAll, Wo, bo, aAll, l);
        comb_part<<<dim3(8, 4, 6), 256, 0, stream>>>(
            aAll, Wc + (size_t)l * 3 * DD * DD, part);
        reduce_add_ln<<<NN, DD, 0, stream>>>(part, 6, bc + (size_t)l * DD, h,
                                             ln1_g + (size_t)l * DD, ln1_b + (size_t)l * DD);
        w1_direct<<<dim3(32, 4), 256, 0, stream>>>(
            h, W1 + (size_t)l * DD * FF, b1 + (size_t)l * FF, f);
        w2_part<<<dim3(8, 4, 8), 256, 0, stream>>>(
            f, W2 + (size_t)l * FF * DD, part);
        reduce_add_ln<<<NN, DD, 0, stream>>>(part, 8, b2 + (size_t)l * DD, h,
                                             ln2_g + (size_t)l * DD, ln2_b + (size_t)l * DD);
    }
    col_mean_part<<<dim3(2, 25), 256, 0, stream>>>(h, headp);
    head_kernel<<<1, 256, 0, stream>>>(headp, head_W, head_b, out);
}

// Round 5
// 1073.660 us; speedup vs baseline: 6.9323x; 1.5020x over previous
//
#include <hip/hip_runtime.h>
#include <math.h>

// Model constants: B=32, T=50000, P=100, D=512, H=16, L=6, C=256
// SCALES=[1,2,4], HS=5 heads/scale, KD=32, N=500 patches, FF=2048, EPS=1e-3.
//
// KEY INSIGHT (round 0, verified): first layernorm is over a size-1 axis ->
// output == ln_in_b[0] everywhere. h is batch-independent; network runs once
// on (500 x 512); final row broadcast x32.
//
// Round 5: attention was LDS-instr-bound on 70 blocks (67us, VALUBusy 5.8%,
// 2.58M conflict cycles). Rework: key-range split (210 blocks), 2 queries per
// thread (halves LDS reads per FMA), pad-36 conflict-free reads, partial
// (o,m,l) + combine pass. qkv gets S=4 k-split (63->252 blocks), W1 S=2.

#define DD 512
#define NN 500
#define HSC 5
#define KDD 32
#define QKVN 160
#define QKV3 480
#define FF 2048
#define NL 6
#define NC 256
#define NB 32
#define LNEPS 1e-3f
#define BM 128
#define BN 64
#define KCH 32

// aAll sub-buffer offsets (floats)
#define AOFF1 256000
#define AOFF2 384000
// total attn rows over scales (500+250+125)
#define RTOT 875
#define OSZ 140000      // RTOT*160
#define MLSZ 4384       // RTOT*5 rounded up

__device__ __forceinline__ float gelu_exact(float x) {
    return 0.5f * x * (1.0f + erff(x * 0.70710678118654752f));
}

// ======================= GEMM core (unchanged engine) =======================
__device__ __forceinline__ void gc_stage(
        const float* __restrict__ A, int lda, int pool_s, float inv_pool, int gather,
        const float* __restrict__ B, int ldb,
        int M, int N, int bm, int bn, int k0,
        int am, int akv, int bk, int bn4, float4* aR, float4* bR) {
    if (!gather) {
        #pragma unroll
        for (int p = 0; p < 4; ++p) {
            int row = bm + p * 32 + am;
            float4 v = make_float4(0.f, 0.f, 0.f, 0.f);
            if (row < M) {
                const float* ap = A + (size_t)row * pool_s * lda + k0 + akv * 4;
                v = *(const float4*)ap;
                for (int t = 1; t < pool_s; ++t) {
                    float4 u = *(const float4*)(ap + (size_t)t * lda);
                    v.x += u.x; v.y += u.y; v.z += u.z; v.w += u.w;
                }
                v.x *= inv_pool; v.y *= inv_pool; v.z *= inv_pool; v.w *= inv_pool;
            }
            aR[p] = v;
        }
    } else {
        int si = k0 >> 9;
        int dd0 = k0 & (DD - 1);
        const float* ap0 = A + (si == 0 ? 0 : (si == 1 ? AOFF1 : AOFF2));
        #pragma unroll
        for (int p = 0; p < 4; ++p) {
            int row = bm + p * 32 + am;
            float4 v = make_float4(0.f, 0.f, 0.f, 0.f);
            if (row < M)
                v = *(const float4*)(ap0 + (size_t)(row >> si) * DD + dd0 + akv * 4);
            aR[p] = v;
        }
    }
    int col = bn + bn4 * 4;
    #pragma unroll
    for (int p = 0; p < 2; ++p) {
        int kk = p * 16 + bk;
        float4 v = make_float4(0.f, 0.f, 0.f, 0.f);
        if (col < N) v = *(const float4*)(B + (size_t)(k0 + kk) * ldb + col);
        bR[p] = v;
    }
}

__device__ __forceinline__ void gemm_core(
        const float* __restrict__ A, int lda, int pool_s, int gather,
        const float* __restrict__ B, int ldb,
        int M, int N, int bm, int bn, int ks, int kend,
        float (&acc)[8][4]) {
    __shared__ float As[KCH][132];
    __shared__ float Bs[KCH][68];
    int tid = threadIdx.x;
    int am = tid >> 3, akv = tid & 7;
    int bk = tid >> 4, bn4 = tid & 15;
    float inv_pool = 1.0f / (float)pool_s;

    float4 aR[4], bR[2];
    gc_stage(A, lda, pool_s, inv_pool, gather, B, ldb, M, N, bm, bn, ks,
             am, akv, bk, bn4, aR, bR);
    int nch = (kend - ks) / KCH;
    int tx = tid & 15, ty = tid >> 4;
    for (int c = 0; c < nch; ++c) {
        __syncthreads();
        #pragma unroll
        for (int p = 0; p < 4; ++p) {
            int m = p * 32 + am;
            As[akv * 4 + 0][m] = aR[p].x;
            As[akv * 4 + 1][m] = aR[p].y;
            As[akv * 4 + 2][m] = aR[p].z;
            As[akv * 4 + 3][m] = aR[p].w;
        }
        #pragma unroll
        for (int p = 0; p < 2; ++p)
            *(float4*)&Bs[p * 16 + bk][bn4 * 4] = bR[p];
        __syncthreads();
        if (c + 1 < nch)
            gc_stage(A, lda, pool_s, inv_pool, gather, B, ldb, M, N, bm, bn,
                     ks + (c + 1) * KCH, am, akv, bk, bn4, aR, bR);
        #pragma unroll
        for (int kk = 0; kk < KCH; ++kk) {
            float4 b  = *(const float4*)&Bs[kk][tx * 4];
            float4 al = *(const float4*)&As[kk][ty * 8];
            float4 ah = *(const float4*)&As[kk][ty * 8 + 4];
            float a8[8] = {al.x, al.y, al.z, al.w, ah.x, ah.y, ah.z, ah.w};
            float b4[4] = {b.x, b.y, b.z, b.w};
            #pragma unroll
            for (int u = 0; u < 8; ++u)
                #pragma unroll
                for (int v = 0; v < 4; ++v)
                    acc[u][v] += a8[u] * b4[v];
        }
    }
}

#define ACC_INIT(acc) { _Pragma("unroll") for (int u=0;u<8;++u) _Pragma("unroll") for (int v=0;v<4;++v) acc[u][v]=0.f; }

// ======================= setup =======================
__global__ void colsum_kernel(const float* __restrict__ pw, float* __restrict__ csum) {
    int d = blockIdx.x * blockDim.x + threadIdx.x;
    if (d < DD) {
        float s = 0.f;
        for (int p = 0; p < 100; ++p) s += pw[p * DD + d];
        csum[d] = s;
    }
}

__global__ void init_h(const float* __restrict__ csum, const float* __restrict__ pb,
                       const float* __restrict__ pos, const float* __restrict__ lnb,
                       float* __restrict__ h) {
    int idx = blockIdx.x * 256 + threadIdx.x;
    if (idx >= NN * DD) return;
    int d = idx & (DD - 1);
    h[idx] = lnb[0] * csum[d] + pb[d] + pos[idx];
}

// ======================= QKV partial (all scales, k-split S=4) =======================
// grid (9, 4, 12): x = which*3 + coltile, y = row tile, z = scale*4 + sp (kq=128)
__global__ __launch_bounds__(256) void qkv_part(
        const float* __restrict__ h,
        const float* __restrict__ Wq, const float* __restrict__ Wk,
        const float* __restrict__ Wv,
        float* __restrict__ part, int l) {
    int scale = blockIdx.z >> 2, sp = blockIdx.z & 3;
    int n = NN >> scale;
    int pool_s = 1 << scale;
    int bm = blockIdx.y * BM;
    if (bm >= n) return;
    int which = blockIdx.x / 3;
    int bn = (blockIdx.x % 3) * BN;
    size_t w = (size_t)(l * 3 + scale);
    const float* W = (which == 0) ? Wq : ((which == 1) ? Wk : Wv);
    float* outb = part + (size_t)sp * 420000
                + (scale == 0 ? 0 : (scale == 1 ? 240000 : 360000));

    float acc[8][4];
    ACC_INIT(acc);
    gemm_core(h, DD, pool_s, 0, W + w * DD * QKVN, QKVN, n, QKVN, bm, bn,
              sp * 128, sp * 128 + 128, acc);

    int tid = threadIdx.x, tx = tid & 15, ty = tid >> 4;
    int col = bn + tx * 4;
    if (col < QKVN) {
        #pragma unroll
        for (int u = 0; u < 8; ++u) {
            int row = bm + ty * 8 + u;
            if (row < n) {
                float4 o;
                o.x = acc[u][0]; o.y = acc[u][1]; o.z = acc[u][2]; o.w = acc[u][3];
                *(float4*)&outb[(size_t)row * QKV3 + which * QKVN + col] = o;
            }
        }
    }
}

__global__ void qkv_reduce(const float* __restrict__ part,
                           const float* __restrict__ bq,
                           const float* __restrict__ bk,
                           const float* __restrict__ bv,
                           float* __restrict__ qkvAll, int l) {
    int idx = blockIdx.x * 256 + threadIdx.x;
    if (idx >= 420000) return;
    int scale, base;
    if (idx < 240000) { scale = 0; base = 0; }
    else if (idx < 360000) { scale = 1; base = 240000; }
    else { scale = 2; base = 360000; }
    int rowrem = (idx - base) % QKV3;
    int which = rowrem / QKVN;
    int col = rowrem - which * QKVN;
    float v = part[idx] + part[420000 + idx] + part[840000 + idx] + part[1260000 + idx];
    v += ((which == 0) ? bq : (which == 1 ? bk : bv))[(size_t)(l * 3 + scale) * QKVN + col];
    qkvAll[idx] = v;
}

// ======================= attention: key-split flash =======================
// grid (8, 5, 7): x = 64-query tile, y = head, z -> (scale, key-split):
// z<4: scale0 sp=z; z in {4,5}: scale1 sp=z-4; z==6: scale2 sp=0.
// 256 threads: kg = tid&7 (8 keys/chunk each), qq = tid>>3 (2 queries: qq, qq+32).
__global__ __launch_bounds__(256) void attn_split(
        const float* __restrict__ qkvAll, float* __restrict__ oPart,
        float* __restrict__ mPart, float* __restrict__ lPart) {
    int z = blockIdx.z;
    int scale, sp;
    if (z < 4)      { scale = 0; sp = z; }
    else if (z < 6) { scale = 1; sp = z - 4; }
    else            { scale = 2; sp = 0; }
    int n = NN >> scale;
    int qt = blockIdx.x;
    if (qt * 64 >= n) return;
    int hh = blockIdx.y;
    int ks = sp * 128;
    int ke = min(n, ks + 128);
    const float* qkv = qkvAll + (scale == 0 ? 0 : (scale == 1 ? 240000 : 360000));
    int rowb = (scale == 0 ? 0 : (scale == 1 ? 500 : 750));

    int tid = threadIdx.x;
    int kg = tid & 7, qq = tid >> 3;
    int q0 = qt * 64 + qq, q1 = q0 + 32;
    bool ok0 = q0 < n, ok1 = q1 < n;

    float qa[32], qb[32];
    {
        const float* p0 = qkv + (size_t)(ok0 ? q0 : 0) * QKV3 + hh * KDD;
        const float* p1 = qkv + (size_t)(ok1 ? q1 : 0) * QKV3 + hh * KDD;
        #pragma unroll
        for (int c4 = 0; c4 < 8; ++c4) {
            float4 v0 = *(const float4*)(p0 + c4 * 4);
            float4 v1 = *(const float4*)(p1 + c4 * 4);
            qa[c4 * 4] = v0.x; qa[c4 * 4 + 1] = v0.y; qa[c4 * 4 + 2] = v0.z; qa[c4 * 4 + 3] = v0.w;
            qb[c4 * 4] = v1.x; qb[c4 * 4 + 1] = v1.y; qb[c4 * 4 + 2] = v1.z; qb[c4 * 4 + 3] = v1.w;
        }
    }

    __shared__ float Ks[64][36];   // pad 36: read banks 4j+c cover all 32 -> conflict-free
    __shared__ float Vs[64][36];
    float o0[32], o1[32];
    #pragma unroll
    for (int c = 0; c < 32; ++c) { o0[c] = 0.f; o1[c] = 0.f; }
    float m0 = -1e30f, m1 = -1e30f, l0 = 0.f, l1 = 0.f;

    int srow = tid >> 2, scol = tid & 3;   // staging: 4 threads/row, 2-way free

    for (int kc = ks; kc < ke; kc += 64) {
        __syncthreads();
        int krow = kc + srow;
        bool ok = krow < ke;
        const float* kp = qkv + (size_t)(ok ? krow : 0) * QKV3 + QKVN + hh * KDD;
        #pragma unroll
        for (int half = 0; half < 2; ++half) {
            int cc = (half * 4 + scol) * 4;
            float4 kv = ok ? *(const float4*)(kp + cc) : make_float4(0.f, 0.f, 0.f, 0.f);
            float4 vv = ok ? *(const float4*)(kp + QKVN + cc) : make_float4(0.f, 0.f, 0.f, 0.f);
            Ks[srow][cc] = kv.x; Ks[srow][cc + 1] = kv.y; Ks[srow][cc + 2] = kv.z; Ks[srow][cc + 3] = kv.w;
            Vs[srow][cc] = vv.x; Vs[srow][cc + 1] = vv.y; Vs[srow][cc + 2] = vv.z; Vs[srow][cc + 3] = vv.w;
        }
        __syncthreads();

        float p0[8], p1[8];
        float cm = -1e30f;
        #pragma unroll
        for (int jj = 0; jj < 8; ++jj) {
            int j = jj * 8 + kg;
            float s0 = 0.f, s1 = 0.f;
            #pragma unroll
            for (int c4 = 0; c4 < 8; ++c4) {
                float4 kv = *(const float4*)&Ks[j][c4 * 4];
                s0 += qa[c4 * 4] * kv.x + qa[c4 * 4 + 1] * kv.y
                    + qa[c4 * 4 + 2] * kv.z + qa[c4 * 4 + 3] * kv.w;
                s1 += qb[c4 * 4] * kv.x + qb[c4 * 4 + 1] * kv.y
                    + qb[c4 * 4 + 2] * kv.z + qb[c4 * 4 + 3] * kv.w;
            }
            s0 *= 0.17677669529663687f;
            s1 *= 0.17677669529663687f;
            if (kc + j >= ke) { s0 = -1e30f; s1 = -1e30f; }
            p0[jj] = s0; p1[jj] = s1;
            cm = fmaxf(cm, fmaxf(s0, s1));
        }
        // reduce chunk max across the 8 kg groups (low 3 lane bits)
        cm = fmaxf(cm, __shfl_xor(cm, 1));
        cm = fmaxf(cm, __shfl_xor(cm, 2));
        cm = fmaxf(cm, __shfl_xor(cm, 4));

        float mn0 = fmaxf(m0, cm), mn1 = fmaxf(m1, cm);
        float al0 = expf(m0 - mn0), al1 = expf(m1 - mn1);
        m0 = mn0; m1 = mn1;
        float ls0 = 0.f, ls1 = 0.f;
        #pragma unroll
        for (int jj = 0; jj < 8; ++jj) {
            p0[jj] = expf(p0[jj] - mn0); ls0 += p0[jj];
            p1[jj] = expf(p1[jj] - mn1); ls1 += p1[jj];
        }
        l0 = l0 * al0 + ls0;
        l1 = l1 * al1 + ls1;
        #pragma unroll
        for (int c = 0; c < 32; ++c) { o0[c] *= al0; o1[c] *= al1; }
        #pragma unroll
        for (int jj = 0; jj < 8; ++jj) {
            int j = jj * 8 + kg;
            float w0 = p0[jj], w1 = p1[jj];
            #pragma unroll
            for (int c4 = 0; c4 < 8; ++c4) {
                float4 vv = *(const float4*)&Vs[j][c4 * 4];
                o0[c4 * 4]     += w0 * vv.x; o0[c4 * 4 + 1] += w0 * vv.y;
                o0[c4 * 4 + 2] += w0 * vv.z; o0[c4 * 4 + 3] += w0 * vv.w;
                o1[c4 * 4]     += w1 * vv.x; o1[c4 * 4 + 1] += w1 * vv.y;
                o1[c4 * 4 + 2] += w1 * vv.z; o1[c4 * 4 + 3] += w1 * vv.w;
            }
        }
    }
    // reduce o,l across the 8 kg groups (m already uniform)
    #pragma unroll
    for (int st = 1; st < 8; st <<= 1) {
        l0 += __shfl_xor(l0, st);
        l1 += __shfl_xor(l1, st);
        #pragma unroll
        for (int c = 0; c < 32; ++c) {
            o0[c] += __shfl_xor(o0[c], st);
            o1[c] += __shfl_xor(o1[c], st);
        }
    }
    if (kg == 0) {
        float* ob = oPart + (size_t)sp * OSZ;
        if (ok0) {
            int r = rowb + q0;
            float* op = ob + (size_t)r * QKVN + hh * KDD;
            #pragma unroll
            for (int c4 = 0; c4 < 8; ++c4) {
                float4 v; v.x = o0[c4*4]; v.y = o0[c4*4+1]; v.z = o0[c4*4+2]; v.w = o0[c4*4+3];
                *(float4*)(op + c4 * 4) = v;
            }
            mPart[sp * MLSZ + r * HSC + hh] = m0;
            lPart[sp * MLSZ + r * HSC + hh] = l0;
        }
        if (ok1) {
            int r = rowb + q1;
            float* op = ob + (size_t)r * QKVN + hh * KDD;
            #pragma unroll
            for (int c4 = 0; c4 < 8; ++c4) {
                float4 v; v.x = o1[c4*4]; v.y = o1[c4*4+1]; v.z = o1[c4*4+2]; v.w = o1[c4*4+3];
                *(float4*)(op + c4 * 4) = v;
            }
            mPart[sp * MLSZ + r * HSC + hh] = m1;
            lPart[sp * MLSZ + r * HSC + hh] = l1;
        }
    }
}

__global__ void attn_combine(const float* __restrict__ oPart,
                             const float* __restrict__ mPart,
                             const float* __restrict__ lPart,
                             float* __restrict__ oAll) {
    int idx = blockIdx.x * 256 + threadIdx.x;
    if (idx >= OSZ) return;
    int rh = idx >> 5;
    int r = rh / HSC, hh = rh - r * HSC;
    int scale = (r < 500) ? 0 : (r < 750 ? 1 : 2);
    int ns = 4 >> scale;
    float M = -1e30f;
    for (int s = 0; s < ns; ++s) M = fmaxf(M, mPart[s * MLSZ + r * HSC + hh]);
    float L = 0.f, val = 0.f;
    for (int s = 0; s < ns; ++s) {
        float wgt = expf(mPart[s * MLSZ + r * HSC + hh] - M);
        L += wgt * lPart[s * MLSZ + r * HSC + hh];
        val += wgt * oPart[(size_t)s * OSZ + idx];
    }
    oAll[idx] = val / L;
}

// ======================= Wo (all scales, bias fused) =======================
__global__ __launch_bounds__(256) void wo_all(
        const float* __restrict__ oAll, const float* __restrict__ Wo,
        const float* __restrict__ bo, float* __restrict__ aAll, int l) {
    int z = blockIdx.z;
    int n = NN >> z;
    if ((int)blockIdx.y * BM >= n) return;
    int bm = blockIdx.y * BM, bn = blockIdx.x * BN;
    size_t w = (size_t)(l * 3 + z);
    const float* A = oAll + (z == 0 ? 0 : (z == 1 ? 80000 : 120000));
    float* C = aAll + (z == 0 ? 0 : (z == 1 ? AOFF1 : AOFF2));
    const float* bias = bo + w * DD;

    float acc[8][4];
    ACC_INIT(acc);
    gemm_core(A, QKVN, 1, 0, Wo + w * QKVN * DD, DD, n, DD, bm, bn, 0, QKVN, acc);

    int tid = threadIdx.x, tx = tid & 15, ty = tid >> 4;
    int col = bn + tx * 4;
    #pragma unroll
    for (int u = 0; u < 8; ++u) {
        int row = bm + ty * 8 + u;
        if (row < n) {
            float4 o;
            o.x = acc[u][0] + bias[col];     o.y = acc[u][1] + bias[col + 1];
            o.z = acc[u][2] + bias[col + 2]; o.w = acc[u][3] + bias[col + 3];
            *(float4*)&C[(size_t)row * DD + col] = o;
        }
    }
}

// ======================= comb partial (gather-A) =======================
__global__ __launch_bounds__(256) void comb_part(
        const float* __restrict__ aAll, const float* __restrict__ Wc,
        float* __restrict__ part) {
    int zz = blockIdx.z;
    int bm = blockIdx.y * BM, bn = blockIdx.x * BN;
    float acc[8][4];
    ACC_INIT(acc);
    gemm_core(aAll, DD, 1, 1, Wc, DD, NN, DD, bm, bn, zz * 256, zz * 256 + 256, acc);
    float* pz = part + (size_t)zz * NN * DD;
    int tid = threadIdx.x, tx = tid & 15, ty = tid >> 4;
    int col = bn + tx * 4;
    #pragma unroll
    for (int u = 0; u < 8; ++u) {
        int row = bm + ty * 8 + u;
        if (row < NN) {
            float4 o;
            o.x = acc[u][0]; o.y = acc[u][1]; o.z = acc[u][2]; o.w = acc[u][3];
            *(float4*)&pz[(size_t)row * DD + col] = o;
        }
    }
}

// ======================= W1 partial (k-split S=2) =======================
__global__ __launch_bounds__(256) void w1_part(
        const float* __restrict__ h, const float* __restrict__ W1,
        float* __restrict__ part) {
    int sp = blockIdx.z;
    int bm = blockIdx.y * BM, bn = blockIdx.x * BN;
    float acc[8][4];
    ACC_INIT(acc);
    gemm_core(h, DD, 1, 0, W1, FF, NN, FF, bm, bn, sp * 256, sp * 256 + 256, acc);
    float* pz = part + (size_t)sp * NN * FF;
    int tid = threadIdx.x, tx = tid & 15, ty = tid >> 4;
    int col = bn + tx * 4;
    #pragma unroll
    for (int u = 0; u < 8; ++u) {
        int row = bm + ty * 8 + u;
        if (row < NN) {
            float4 o;
            o.x = acc[u][0]; o.y = acc[u][1]; o.z = acc[u][2]; o.w = acc[u][3];
            *(float4*)&pz[(size_t)row * FF + col] = o;
        }
    }
}

__global__ void w1_reduce(const float* __restrict__ part,
                          const float* __restrict__ b1, float* __restrict__ f) {
    int idx = blockIdx.x * 256 + threadIdx.x;
    if (idx >= NN * FF) return;
    f[idx] = gelu_exact(part[idx] + part[NN * FF + idx] + b1[idx & (FF - 1)]);
}

// ======================= W2 partial =======================
__global__ __launch_bounds__(256) void w2_part(
        const float* __restrict__ f, const float* __restrict__ W2,
        float* __restrict__ part) {
    int zz = blockIdx.z;
    int bm = blockIdx.y * BM, bn = blockIdx.x * BN;
    float acc[8][4];
    ACC_INIT(acc);
    gemm_core(f, FF, 1, 0, W2, DD, NN, DD, bm, bn, zz * 256, zz * 256 + 256, acc);
    float* pz = part + (size_t)zz * NN * DD;
    int tid = threadIdx.x, tx = tid & 15, ty = tid >> 4;
    int col = bn + tx * 4;
    #pragma unroll
    for (int u = 0; u < 8; ++u) {
        int row = bm + ty * 8 + u;
        if (row < NN) {
            float4 o;
            o.x = acc[u][0]; o.y = acc[u][1]; o.z = acc[u][2]; o.w = acc[u][3];
            *(float4*)&pz[(size_t)row * DD + col] = o;
        }
    }
}

// ======================= fused reduce + bias + residual + LN =======================
__global__ void reduce_add_ln(const float* __restrict__ part, int S,
                              const float* __restrict__ bias,
                              float* __restrict__ h,
                              const float* __restrict__ gw,
                              const float* __restrict__ bw) {
    int row = blockIdx.x, t = threadIdx.x;
    size_t idx = (size_t)row * DD + t;
    float x = h[idx] + bias[t];
    for (int s = 0; s < S; ++s) x += part[(size_t)s * NN * DD + idx];
    int lane = t & 63, wv = t >> 6;
    __shared__ float s1[8], s2[8];
    __shared__ float mb[2];
    float sum = x, sq = x * x;
    for (int off = 32; off; off >>= 1) {
        sum += __shfl_down(sum, off);
        sq  += __shfl_down(sq,  off);
    }
    if (lane == 0) { s1[wv] = sum; s2[wv] = sq; }
    __syncthreads();
    if (t == 0) {
        float a = 0.f, b = 0.f;
        for (int i = 0; i < 8; ++i) { a += s1[i]; b += s2[i]; }
        float mean = a / (float)DD;
        float var = b / (float)DD - mean * mean;
        mb[0] = mean;
        mb[1] = rsqrtf(var + LNEPS);
    }
    __syncthreads();
    h[idx] = (x - mb[0]) * mb[1] * gw[t] + bw[t];
}

// ======================= head =======================
__global__ void col_mean_part(const float* __restrict__ h, float* __restrict__ partial) {
    int col = blockIdx.x * 256 + threadIdx.x;
    int r0 = blockIdx.y * 20;
    float s = 0.f;
    #pragma unroll
    for (int r = 0; r < 20; ++r) s += h[(size_t)(r0 + r) * DD + col];
    partial[(size_t)blockIdx.y * DD + col] = s;
}

__global__ void head_kernel(const float* __restrict__ partial,
                            const float* __restrict__ hw,
                            const float* __restrict__ hb, float* __restrict__ out) {
    __shared__ float gs[DD];
    __shared__ float r[4];
    __shared__ float bmx, bsum;
    int t = threadIdx.x;
    for (int d = t; d < DD; d += 256) {
        float s = 0.f;
        #pragma unroll
        for (int p = 0; p < 25; ++p) s += partial[(size_t)p * DD + d];
        gs[d] = s / (float)NN;
    }
    __syncthreads();
    float acc = hb[t];
    #pragma unroll 16
    for (int d = 0; d < DD; ++d) acc += gs[d] * hw[(size_t)d * NC + t];
    int lane = t & 63, wv = t >> 6;
    float mx = acc;
    for (int off = 32; off; off >>= 1) mx = fmaxf(mx, __shfl_down(mx, off));
    if (lane == 0) r[wv] = mx;
    __syncthreads();
    if (t == 0) bmx = fmaxf(fmaxf(r[0], r[1]), fmaxf(r[2], r[3]));
    __syncthreads();
    float e = expf(acc - bmx);
    float s = e;
    for (int off = 32; off; off >>= 1) s += __shfl_down(s, off);
    if (lane == 0) r[wv] = s;
    __syncthreads();
    if (t == 0) bsum = 1.f / (r[0] + r[1] + r[2] + r[3]);
    __syncthreads();
    float pv = e * bsum;
    for (int b = 0; b < NB; ++b) out[(size_t)b * NC + t] = pv;
}

extern "C" void kernel_launch(void* const* d_in, const int* in_sizes, int n_in,
                              void* d_out, int out_size, void* d_ws, size_t ws_size,
                              hipStream_t stream) {
    const float* ln_in_b = (const float*)d_in[2];
    const float* patch_W = (const float*)d_in[3];
    const float* patch_b = (const float*)d_in[4];
    const float* pos_emb = (const float*)d_in[5];
    const float* Wq = (const float*)d_in[6];
    const float* bq = (const float*)d_in[7];
    const float* Wk = (const float*)d_in[8];
    const float* bk = (const float*)d_in[9];
    const float* Wv = (const float*)d_in[10];
    const float* bv = (const float*)d_in[11];
    const float* Wo = (const float*)d_in[12];
    const float* bo = (const float*)d_in[13];
    const float* Wc = (const float*)d_in[14];
    const float* bc = (const float*)d_in[15];
    const float* ln1_g = (const float*)d_in[16];
    const float* ln1_b = (const float*)d_in[17];
    const float* W1 = (const float*)d_in[18];
    const float* b1 = (const float*)d_in[19];
    const float* W2 = (const float*)d_in[20];
    const float* b2 = (const float*)d_in[21];
    const float* ln2_g = (const float*)d_in[22];
    const float* ln2_b = (const float*)d_in[23];
    const float* head_W = (const float*)d_in[24];
    const float* head_b = (const float*)d_in[25];
    float* out = (float*)d_out;

    // workspace (floats), aliased: qkvPart shares `part`; oPart/ml share `f`.
    float* ws = (float*)d_ws;
    float* h      = ws;                  // 256000
    float* csum   = h + 256000;          // 1024
    float* qkvAll = csum + 1024;         // 420000
    float* oAll   = qkvAll + 420000;     // 140000
    float* aAll   = oAll + 140000;       // 448000
    float* f      = aAll + 448000;       // 1024000  (also oPart+ml between attn/combine)
    float* part   = f + 1024000;         // 2048000  (also qkvPart 1680000)
    float* headp  = part + 2048000;      // 12800
    float* oPart  = f;                   // 4*140000 = 560000
    float* mPart  = f + 560000;          // 4*4384
    float* lPart  = mPart + 4 * MLSZ;    // 4*4384
    float* qkvP   = part;                // 4*420000 = 1680000

    colsum_kernel<<<1, 512, 0, stream>>>(patch_W, csum);
    init_h<<<(NN * DD + 255) / 256, 256, 0, stream>>>(csum, patch_b, pos_emb, ln_in_b, h);

    for (int l = 0; l < NL; ++l) {
        qkv_part<<<dim3(9, 4, 12), 256, 0, stream>>>(h, Wq, Wk, Wv, qkvP, l);
        qkv_reduce<<<(420000 + 255) / 256, 256, 0, stream>>>(qkvP, bq, bk, bv, qkvAll, l);
        attn_split<<<dim3(8, HSC, 7), 256, 0, stream>>>(qkvAll, oPart, mPart, lPart);
        attn_combine<<<(OSZ + 255) / 256, 256, 0, stream>>>(oPart, mPart, lPart, oAll);
        wo_all<<<dim3(8, 4, 3), 256, 0, stream>>>(oAll, Wo, bo, aAll, l);
        comb_part<<<dim3(8, 4, 6), 256, 0, stream>>>(
            aAll, Wc + (size_t)l * 3 * DD * DD, part);
        reduce_add_ln<<<NN, DD, 0, stream>>>(part, 6, bc + (size_t)l * DD, h,
                                             ln1_g + (size_t)l * DD, ln1_b + (size_t)l * DD);
        w1_part<<<dim3(32, 4, 2), 256, 0, stream>>>(h, W1 + (size_t)l * DD * FF, part);
        w1_reduce<<<(NN * FF + 255) / 256, 256, 0, stream>>>(
            part, b1 + (size_t)l * FF, f);
        w2_part<<<dim3(8, 4, 8), 256, 0, stream>>>(f, W2 + (size_t)l * FF * DD, part);
        reduce_add_ln<<<NN, DD, 0, stream>>>(part, 8, b2 + (size_t)l * DD, h,
                                             ln2_g + (size_t)l * DD, ln2_b + (size_t)l * DD);
    }
    col_mean_part<<<dim3(2, 25), 256, 0, stream>>>(h, headp);
    head_kernel<<<1, 256, 0, stream>>>(headp, head_W, head_b, out);
}